// Round 4
// baseline (1712.597 us; speedup 1.0000x reference)
//
#include <hip/hip_runtime.h>
#include <cstdint>

typedef unsigned short u16;
typedef __bf16  bf16x8 __attribute__((ext_vector_type(8)));
typedef float   f32x4  __attribute__((ext_vector_type(4)));

#define S_LEN 3072
#define DMODEL 1024

__device__ __forceinline__ float bf2f(u16 u){ return __uint_as_float(((unsigned)u) << 16); }
__device__ __forceinline__ u16 f2bf(float f){
    unsigned u = __float_as_uint(f);
    return (u16)((u + 0x7fffu + ((u >> 16) & 1u)) >> 16);
}
// mode-aware element fetch -> bf16 bits (mode 0: bf16 input; mode 1: fp32 input)
__device__ __forceinline__ u16 cvld(const void* p, long i, int mode){
    return mode ? f2bf(((const float*)p)[i]) : ((const u16*)p)[i];
}

__device__ __forceinline__ void async16(const void* g, void* l){
    __builtin_amdgcn_global_load_lds(
        (const __attribute__((address_space(1))) unsigned int*)g,
        (__attribute__((address_space(3))) unsigned int*)l, 16, 0, 0);
}

// ---------------------------------------------------------------------------
// dtype sniffer (round-3 proven): flag[0]=1 if inputs are fp32, 0 if bf16.
// ---------------------------------------------------------------------------
__global__ void sniff_kernel(const u16* __restrict__ x, int* __restrict__ flag)
{
    __shared__ int r[256];
    int tid = threadIdx.x, w = 0;
    for (int j = tid; j < 4096; j += 256){
        int e = (x[j] >> 7) & 0xFF;
        if (e < 90 || e > 140) w++;
    }
    r[tid] = w; __syncthreads();
    for (int s = 128; s > 0; s >>= 1){ if (tid < s) r[tid] += r[tid + s]; __syncthreads(); }
    if (tid == 0){ flag[0] = (r[0] > 256) ? 1 : 0; flag[1] = 0; }
}

// ---------------------------------------------------------------------------
// NT GEMM: C[M,N] = A[M,K](row,lda,bf16) * B[N,K]^T(row,ldb,bf16)
// m97 structure: 128x128 tile, BK=64, async global_load_lds x16B, linear LDS,
// 4 waves x (4x4) mfma_f32_16x16x32_bf16.
// SPLIT>1: z = batch*SPLIT + sp; each sp does K/SPLIT; writes fp32 partial at
//          (float*)Cv + sp*pStride + batch*cBS + row*ldc + col (no bias).
// SPLIT==1: bf16 out + optional bias; SPLITN scatters cols into stacked mats.
// ---------------------------------------------------------------------------
template<int SPLIT, bool SPLITN>
__global__ __launch_bounds__(256)
void gemm_nt(const u16* __restrict__ A, int lda,
             const u16* __restrict__ B, int ldb,
             void* __restrict__ Cv, int ldc,
             const u16* __restrict__ bias,
             int K, int splitRows,
             long aBS, long bBS, long cBS, long pStride)
{
    __shared__ __align__(16) u16 Abuf[128 * 64];
    __shared__ __align__(16) u16 Bbuf[128 * 64];
    const int tid  = threadIdx.x;
    const int lane = tid & 63, wid = tid >> 6;
    const int wm = wid >> 1, wn = wid & 1;
    const int quad = lane >> 4, lr = lane & 15;

    const int z   = blockIdx.z;
    const int bat = z / SPLIT;
    const int sp  = z % SPLIT;
    const int kLen = K / SPLIT;

    A += (long)bat * aBS + (long)blockIdx.x * 128 * lda + (long)sp * kLen;
    B += (long)bat * bBS + (long)blockIdx.y * 128 * ldb + (long)sp * kLen;

    f32x4 zero = {0.f, 0.f, 0.f, 0.f};
    f32x4 acc[4][4];
#pragma unroll
    for (int i = 0; i < 4; i++)
#pragma unroll
        for (int j = 0; j < 4; j++) acc[i][j] = zero;

    int um[4], ukq[4];
#pragma unroll
    for (int i = 0; i < 4; i++){
        int u = i * 256 + tid;
        um[i]  = u >> 3;       // row within 128-tile
        ukq[i] = u & 7;        // 16B unit within 64-wide K slab (linear m97 layout)
    }

    const int kTiles = kLen >> 6;
    for (int kt = 0; kt < kTiles; ++kt){
        const int k0 = kt << 6;
        __syncthreads();   // previous iteration's ds_reads done
#pragma unroll
        for (int i = 0; i < 4; i++)
            async16(A + (long)um[i] * lda + k0 + ukq[i] * 8, Abuf + (i * 256 + tid) * 8);
#pragma unroll
        for (int i = 0; i < 4; i++)
            async16(B + (long)um[i] * ldb + k0 + ukq[i] * 8, Bbuf + (i * 256 + tid) * 8);
        __syncthreads();   // vmcnt drained by compiler before barrier
#pragma unroll
        for (int ks = 0; ks < 2; ++ks){
            bf16x8 af[4], bfg[4];
#pragma unroll
            for (int t = 0; t < 4; t++){
                int m  = wm * 64 + t * 16 + lr;
                af[t]  = *(const bf16x8*)(Abuf + (m * 8 + ks * 4 + quad) * 8);
                int n  = wn * 64 + t * 16 + lr;
                bfg[t] = *(const bf16x8*)(Bbuf + (n * 8 + ks * 4 + quad) * 8);
            }
#pragma unroll
            for (int mt = 0; mt < 4; mt++)
#pragma unroll
                for (int nt = 0; nt < 4; nt++)
                    acc[mt][nt] = __builtin_amdgcn_mfma_f32_16x16x32_bf16(
                        af[mt], bfg[nt], acc[mt][nt], 0, 0, 0);
        }
    }

    const int rowBase = blockIdx.x * 128 + wm * 64;
    const int colBase = blockIdx.y * 128 + wn * 64;
#pragma unroll
    for (int mt = 0; mt < 4; ++mt){
#pragma unroll
        for (int nt = 0; nt < 4; ++nt){
            const int col = colBase + nt * 16 + lr;
            float bv2 = (SPLIT == 1 && bias) ? bf2f(bias[col]) : 0.f;
#pragma unroll
            for (int r = 0; r < 4; r++){
                int row = rowBase + mt * 16 + quad * 4 + r;   // C/D: col=lane&15, row=quad*4+reg
                float v = acc[mt][nt][r] + bv2;
                if (SPLIT == 1){
                    long idx;
                    if (SPLITN) idx = ((long)(col >> 10) * splitRows + row) * DMODEL + (col & (DMODEL - 1));
                    else        idx = (long)row * ldc + col;
                    ((u16*)Cv)[(long)bat * cBS + idx] = f2bf(v);
                } else {
                    float* P = (float*)Cv + (long)sp * pStride + (long)bat * cBS;
                    P[(long)row * ldc + col] = v;
                }
            }
        }
    }
}

// ---------------------------------------------------------------------------
// mode-aware tiled transpose: out[C,R] = in[R,C]^T (bf16 out), batched over z
// ---------------------------------------------------------------------------
__global__ __launch_bounds__(256)
void transpose_cvt(const int* __restrict__ flag, const void* __restrict__ in, long srcOff,
                   u16* __restrict__ out, int R, int C, long inB, long outB)
{
    __shared__ u16 t[32][34];
    const int mode = *flag;
    const long ib = srcOff + (long)blockIdx.z * inB;
    u16* op = out + (long)blockIdx.z * outB;
    int c0 = blockIdx.x * 32, r0 = blockIdx.y * 32;
    int tx = threadIdx.x, ty = threadIdx.y;
#pragma unroll
    for (int j = 0; j < 4; j++){
        int r = r0 + ty + j * 8;
        t[ty + j * 8][tx] = cvld(in, ib + (long)r * C + c0 + tx, mode);
    }
    __syncthreads();
#pragma unroll
    for (int j = 0; j < 4; j++){
        int c = c0 + ty + j * 8;
        op[(long)c * R + r0 + tx] = t[tx][ty + j * 8];
    }
}

__global__ __launch_bounds__(256)
void init_h(const int* __restrict__ flag, const void* __restrict__ hin,
            float* __restrict__ h, u16* __restrict__ hbf)
{
    const int mode = *flag;
    long i = (long)blockIdx.x * 256 + threadIdx.x;
    u16 u = cvld(hin, i, mode);
    h[i]   = bf2f(u);
    hbf[i] = u;
}

// copy Wq|Wk|Wv of layer l into one contiguous bf16 buffer (for z-batched GEMM)
__global__ __launch_bounds__(256)
void cvt3_kernel(const int* __restrict__ flag, const void* Wq, const void* Wk,
                 const void* Wv, int l, u16* __restrict__ dst)
{
    const int mode = *flag;
    long i = (long)blockIdx.x * 256 + threadIdx.x;   // < 3*1048576
    int z = (int)(i >> 20);
    long r = i & 1048575;
    const void* src = (z == 0) ? Wq : (z == 1) ? Wk : Wv;
    dst[i] = cvld(src, (long)l * 1048576 + r, mode);
}

// bias arena layout (elements)
#define OFF_BQKV 0
#define OFF_BH   12288
#define OFF_BO   16384
#define OFF_BF1  20480
#define OFF_BF2  28672
#define OFF_G1   32768
#define OFF_B1N  36864
#define OFF_G2   40960
#define OFF_B2N  45056
#define OFF_WHD  49152
#define OFF_BHD  53248
#define BIAS_TOT 53252

__global__ __launch_bounds__(256)
void cvt_biases(const int* __restrict__ flag,
                const void* bq, const void* bk, const void* bv, const void* bh,
                const void* bo, const void* bf1, const void* bf2,
                const void* g1, const void* b1n, const void* g2, const void* b2n,
                const void* whd, const void* bhd, u16* __restrict__ A)
{
    int i = blockIdx.x * 256 + threadIdx.x;
    if (i >= BIAS_TOT) return;
    const int mode = *flag;
    u16 v;
    if (i < OFF_BH){
        int l = i / 3072, r = i % 3072;
        const void* p = (r < 1024) ? bq : (r < 2048) ? bk : bv;
        v = cvld(p, (long)l * 1024 + (r & 1023), mode);
    }
    else if (i < OFF_BO)  v = cvld(bh,  i - OFF_BH, mode);
    else if (i < OFF_BF1) v = cvld(bo,  i - OFF_BO, mode);
    else if (i < OFF_BF2) v = cvld(bf1, i - OFF_BF1, mode);
    else if (i < OFF_G1)  v = cvld(bf2, i - OFF_BF2, mode);
    else if (i < OFF_B1N) v = cvld(g1,  i - OFF_G1, mode);
    else if (i < OFF_G2)  v = cvld(b1n, i - OFF_B1N, mode);
    else if (i < OFF_B2N) v = cvld(g2,  i - OFF_G2, mode);
    else if (i < OFF_WHD) v = cvld(b2n, i - OFF_B2N, mode);
    else if (i < OFF_BHD) v = cvld(whd, i - OFF_WHD, mode);
    else                  v = cvld(bhd, i - OFF_BHD, mode);
    A[i] = v;
}

// combined QKV+head bias: bqkvh[z*1024+n] = sum_d b_z[d]*WhT[n,d] + bh[l,n]
__global__ __launch_bounds__(256)
void bias_combine(const u16* __restrict__ arena, const u16* __restrict__ WhT,
                  int l, u16* __restrict__ bqkvh)
{
    int i = blockIdx.x * 256 + threadIdx.x;   // < 3072
    int z = i >> 10, n = i & 1023;
    const u16* bz = arena + OFF_BQKV + l * 3072 + z * 1024;
    const u16* wr = WhT + (long)n * 1024;
    float s = bf2f(arena[OFF_BH + l * 1024 + n]);
    for (int d = 0; d < 1024; d += 8){
        bf16x8 w = *(const bf16x8*)(wr + d);
        bf16x8 b = *(const bf16x8*)(bz + d);
#pragma unroll
        for (int j = 0; j < 8; j++) s += (float)w[j] * (float)b[j];
    }
    bqkvh[i] = f2bf(s);
}

__device__ __forceinline__ float blockSum(float v, float* red){
    int lane = threadIdx.x & 63, wid = threadIdx.x >> 6;
#pragma unroll
    for (int o = 32; o > 0; o >>= 1) v += __shfl_down(v, o, 64);
    __syncthreads();
    if (lane == 0) red[wid] = v;
    __syncthreads();
    return red[0] + red[1] + red[2] + red[3];
}
__device__ __forceinline__ float blockMax(float v, float* red){
    int lane = threadIdx.x & 63, wid = threadIdx.x >> 6;
#pragma unroll
    for (int o = 32; o > 0; o >>= 1) v = fmaxf(v, __shfl_down(v, o, 64));
    __syncthreads();
    if (lane == 0) red[wid] = v;
    __syncthreads();
    return fmaxf(fmaxf(red[0], red[1]), fmaxf(red[2], red[3]));
}

// h = LN(h + bias + sum_{s<4} parts[s]) * g + b ; fp32 h in place, bf16 copy
__global__ __launch_bounds__(256)
void ln_fused(float* __restrict__ h, const float* __restrict__ parts, long pStride,
              const u16* __restrict__ bias, u16* __restrict__ hbf,
              const u16* __restrict__ g, const u16* __restrict__ b)
{
    __shared__ float red[4];
    long base = (long)blockIdx.x * DMODEL;
    int tid = threadIdx.x;
    float v[4];
    float s = 0.f;
#pragma unroll
    for (int j = 0; j < 4; j++){
        int c = tid + j * 256;
        float x = bf2f(bias[c]);
#pragma unroll
        for (int sp = 0; sp < 4; sp++) x += parts[(long)sp * pStride + base + c];
        float r = h[base + c] + x;
        v[j] = r; s += r;
    }
    float mu = blockSum(s, red) * (1.f / DMODEL);
    float s2 = 0.f;
#pragma unroll
    for (int j = 0; j < 4; j++){ float d = v[j] - mu; s2 += d * d; }
    float var = blockSum(s2, red) * (1.f / DMODEL);
    float inv = rsqrtf(var + 1e-5f);
#pragma unroll
    for (int j = 0; j < 4; j++){
        int c = tid + j * 256;
        float y = (v[j] - mu) * inv * bf2f(g[c]) + bf2f(b[c]);
        h[base + c]   = y;
        hbf[base + c] = f2bf(y);
    }
}

// sum nsplit fp32 partials -> bf16 (4 elems/thread)
__global__ __launch_bounds__(256)
void reduce_ctx(const float* __restrict__ parts, long pStride, int nsplit,
                u16* __restrict__ out)
{
    long i0 = ((long)blockIdx.x * 256 + threadIdx.x) * 4;
#pragma unroll
    for (int j = 0; j < 4; j++){
        long i = i0 + j;
        float s = 0.f;
        for (int sp = 0; sp < nsplit; sp++) s += parts[(long)sp * pStride + i];
        out[i] = f2bf(s);
    }
}

// sum 2 fp32 partials + bias, relu -> bf16 (ffn1), ncols = 2048
__global__ __launch_bounds__(256)
void reduce_relu(const float* __restrict__ parts, long pStride,
                 const u16* __restrict__ bias, u16* __restrict__ out)
{
    long i0 = ((long)blockIdx.x * 256 + threadIdx.x) * 4;
#pragma unroll
    for (int j = 0; j < 4; j++){
        long i = i0 + j;
        float s = parts[i] + parts[pStride + i] + bf2f(bias[(int)(i & 2047)]);
        out[i] = f2bf(fmaxf(s, 0.f));
    }
}

// in-place row softmax (bf16, row length S_LEN), scale 1/sqrt(DK)
__global__ __launch_bounds__(256)
void softmax_kernel(u16* __restrict__ P)
{
    __shared__ float red[4];
    u16* row = P + ((long)blockIdx.y * S_LEN + blockIdx.x) * S_LEN;
    int tid = threadIdx.x;
    const float scale = 0.0625f;    // 1/sqrt(256)
    float x[12];
    float m = -1e30f;
#pragma unroll
    for (int j = 0; j < 12; j++){
        x[j] = bf2f(row[tid + j * 256]) * scale;
        m = fmaxf(m, x[j]);
    }
    m = blockMax(m, red);
    float s = 0.f;
#pragma unroll
    for (int j = 0; j < 12; j++){ x[j] = __expf(x[j] - m); s += x[j]; }
    s = blockSum(s, red);
    float inv = 1.f / s;
#pragma unroll
    for (int j = 0; j < 12; j++) row[tid + j * 256] = f2bf(x[j] * inv);
}

__global__ __launch_bounds__(256)
void head_kernel(const int* __restrict__ flag, const float* __restrict__ h,
                 const u16* __restrict__ arena, const int* __restrict__ nePtr,
                 const int* __restrict__ naPtr, void* __restrict__ outp)
{
    __shared__ float red[4];
    int o = blockIdx.x;
    int ne = *nePtr, na = *naPtr;
    int widx, row;
    if (o < 3 * na){ widx = o / na; row = ne + o % na; }
    else           { widx = 3;      row = o - 3 * na; }
    int tid = threadIdx.x;
    const float* hr = h + (long)row * DMODEL;
    const u16*   w  = arena + OFF_WHD + widx * DMODEL;
    float s = 0.f;
#pragma unroll
    for (int j = 0; j < 4; j++){ int c = tid + j * 256; s += hr[c] * bf2f(w[c]); }
    s = blockSum(s, red);
    if (tid == 0){
        float r = s + bf2f(arena[OFF_BHD + widx]);
        if (*flag) ((float*)outp)[o] = r;
        else       ((u16*)outp)[o]   = f2bf(r);
    }
}

// ---------------------------------------------------------------------------
extern "C" void kernel_launch(void* const* d_in, const int* in_sizes, int n_in,
                              void* d_out, int out_size, void* d_ws, size_t ws_size,
                              hipStream_t stream)
{
    const void* hidden = d_in[0];
    const void* Wq  = d_in[1];  const void* bq  = d_in[2];
    const void* Wk  = d_in[3];  const void* bk  = d_in[4];
    const void* Wv  = d_in[5];  const void* bv  = d_in[6];
    const void* Wh  = d_in[7];  const void* bh  = d_in[8];
    const void* Wo  = d_in[9];  const void* bo  = d_in[10];
    const void* g1  = d_in[11]; const void* b1n = d_in[12];
    const void* g2  = d_in[13]; const void* b2n = d_in[14];
    const void* Wf1 = d_in[15]; const void* bf1 = d_in[16];
    const void* Wf2 = d_in[17]; const void* bf2 = d_in[18];
    const void* Whd = d_in[19]; const void* bhd = d_in[20];
    const int* nePtr = (const int*)d_in[21];
    const int* naPtr = (const int*)d_in[22];

    const long D = 1024, S = 3072, L = 4, DK = 256;

    char* ws = (char*)d_ws;
    size_t off = 0;
    auto alloc = [&](size_t bytes)->char*{
        char* p = ws + off;
        off = (off + bytes + 255) & ~(size_t)255;
        return p;
    };
    int*  flag   = (int*)alloc(256);
    u16*  barena = (u16*)alloc(BIAS_TOT * 2);
    u16*  bqkvh  = (u16*)alloc(3 * D * 2);
    u16*  WhT    = (u16*)alloc(D * D * 2);
    u16*  WqkvhT = (u16*)alloc(3 * D * D * 2);     // combined (Wz@Wh)^T, (3072 x 1024)
    u16*  WoT    = (u16*)alloc(D * D * 2);
    u16*  Wf1T   = (u16*)alloc(2 * D * D * 2);
    u16*  Wf2T   = (u16*)alloc(2 * D * D * 2);
    float* h     = (float*)alloc(S * D * 4);
    u16*  hbf    = (u16*)alloc(S * D * 2);
    u16*  qkvh   = (u16*)alloc(3 * S * D * 2);     // [Qh;Kh;Vh] stacked
    char* regionA = alloc(2 * S * D * 2);          // vhT (D x S) + ctx (S x D)
    size_t baseEnd = off;

    // scores region: HB=4 needs 75.5 MB; HB=1 needs 63 MB (ffn1 + ffn1 partials)
    size_t reg4 = (size_t)4 * S * S * 2;
    size_t reg1 = (size_t)S * 2 * D * 2 + (size_t)2 * S * 2 * D * 4;
    int HBv = (ws_size >= baseEnd + reg4 + 4096) ? 4 : 1;
    char* regionB = alloc(HBv == 4 ? reg4 : reg1);
    size_t endB = off;
    size_t cp1 = (size_t)S * D * 4;
    int ctxSplit = (ws_size >= endB + 4 * cp1 + 4096) ? 4
                 : (ws_size >= endB + 2 * cp1 + 4096) ? 2 : 1;
    float* ctxParts = (float*)alloc(ctxSplit > 1 ? (size_t)ctxSplit * cp1 : 0);

    u16* vhT     = (u16*)regionA;                  // (D x S)
    u16* ctx     = (u16*)regionA + D * S;          // (S x D)
    u16* scoresP = (u16*)regionB;
    u16* Wcat    = (u16*)regionB;                  // [Wq;Wk;Wv] contiguous (prep)
    float* woParts = (float*)regionB;              // 4 x (S*D) fp32 (scores dead)
    u16* ffn1    = (u16*)regionB;                  // (S x 2048) bf16
    float* f1Parts = (float*)(regionB + (size_t)S * 2 * D * 2);
    float* f2Parts = (float*)(regionB + (size_t)S * 2 * D * 2);

    const long pSD = S * D;       // fp32 elems per S*1024 partial
    const long pSF = S * 2 * D;   // fp32 elems per S*2048 partial

    dim3 tb(32, 8);
    sniff_kernel<<<1, 256, 0, stream>>>((const u16*)hidden, flag);
    cvt_biases<<<(BIAS_TOT + 255) / 256, 256, 0, stream>>>(
        flag, bq, bk, bv, bh, bo, bf1, bf2, g1, b1n, g2, b2n, Whd, bhd, barena);
    init_h<<<(int)(S * D / 256), 256, 0, stream>>>(flag, hidden, h, hbf);

    for (int l = 0; l < L; ++l){
        // ---- weight prep ----
        transpose_cvt<<<dim3(8, 32, 4), tb, 0, stream>>>(flag, Wh, (long)l * 4 * D * DK, WhT, 1024, 256, D * DK, D * DK);
        cvt3_kernel<<<12288, 256, 0, stream>>>(flag, Wq, Wk, Wv, l, Wcat);
        // WqkvhT[z*1024+n, c] = sum_d WhT[n,d] * Wcat[z][c,d]
        gemm_nt<1, false><<<dim3(8, 8, 3), 256, 0, stream>>>(
            WhT, 1024, Wcat, 1024, WqkvhT, 1024, nullptr,
            1024, 0, 0, (long)D * D, (long)D * D, 0);
        bias_combine<<<12, 256, 0, stream>>>(barena, WhT, l, bqkvh);
        transpose_cvt<<<dim3(32, 32, 1), tb, 0, stream>>>(flag, Wo, (long)l * D * D, WoT, 1024, 1024, 0, 0);
        transpose_cvt<<<dim3(64, 32, 1), tb, 0, stream>>>(flag, Wf1, (long)l * 2 * D * D, Wf1T, 1024, 2048, 0, 0);
        transpose_cvt<<<dim3(32, 64, 1), tb, 0, stream>>>(flag, Wf2, (long)l * 2 * D * D, Wf2T, 2048, 1024, 0, 0);

        // ---- fused QKV+head projection ----
        gemm_nt<1, true><<<dim3(24, 24, 1), 256, 0, stream>>>(
            hbf, 1024, WqkvhT, 1024, qkvh, 0, bqkvh,
            1024, (int)S, 0, 0, 0, 0);
        transpose_cvt<<<dim3(32, 96, 1), tb, 0, stream>>>(flag + 1, qkvh, 2 * S * D, vhT, (int)S, (int)D, 0, 0);

        // ---- attention ----
        for (int h0 = 0; h0 < 4; h0 += HBv){
            gemm_nt<1, false><<<dim3(24, 24, HBv), 256, 0, stream>>>(
                qkvh + h0 * DK, 1024, qkvh + S * D + h0 * DK, 1024,
                scoresP, (int)S, nullptr, (int)DK, 0, DK, DK, (long)S * S, 0);
            softmax_kernel<<<dim3(3072, HBv), 256, 0, stream>>>(scoresP);
            if (ctxSplit == 4)
                gemm_nt<4, false><<<dim3(24, 2, HBv * 4), 256, 0, stream>>>(
                    scoresP, (int)S, vhT + (long)h0 * DK * S, (int)S,
                    ctxParts + h0 * DK, 1024, nullptr, (int)S, 0,
                    (long)S * S, (long)DK * S, DK, pSD);
            else if (ctxSplit == 2)
                gemm_nt<2, false><<<dim3(24, 2, HBv * 2), 256, 0, stream>>>(
                    scoresP, (int)S, vhT + (long)h0 * DK * S, (int)S,
                    ctxParts + h0 * DK, 1024, nullptr, (int)S, 0,
                    (long)S * S, (long)DK * S, DK, pSD);
            else
                gemm_nt<1, false><<<dim3(24, 2, HBv), 256, 0, stream>>>(
                    scoresP, (int)S, vhT + (long)h0 * DK * S, (int)S,
                    ctx + h0 * DK, 1024, nullptr, (int)S, 0,
                    (long)S * S, (long)DK * S, DK, 0);
        }
        if (ctxSplit > 1)
            reduce_ctx<<<3072, 256, 0, stream>>>(ctxParts, pSD, ctxSplit, ctx);

        // ---- attn_out: split-K=4; reduce fused into LN ----
        gemm_nt<4, false><<<dim3(24, 8, 4), 256, 0, stream>>>(
            ctx, 1024, WoT, 1024, woParts, 1024, nullptr,
            1024, 0, 0, 0, 0, pSD);
        ln_fused<<<3072, 256, 0, stream>>>(h, woParts, pSD, barena + OFF_BO + l * D,
                                           hbf, barena + OFF_G1 + l * D, barena + OFF_B1N + l * D);
        // ---- FFN1: split-K=2; reduce+bias+relu ----
        gemm_nt<2, false><<<dim3(24, 16, 2), 256, 0, stream>>>(
            hbf, 1024, Wf1T, 1024, f1Parts, 2048, nullptr,
            1024, 0, 0, 0, 0, pSF);
        reduce_relu<<<6144, 256, 0, stream>>>(f1Parts, pSF, barena + OFF_BF1 + l * 2 * D, ffn1);
        // ---- FFN2: split-K=4; reduce fused into LN ----
        gemm_nt<4, false><<<dim3(24, 8, 4), 256, 0, stream>>>(
            ffn1, 2048, Wf2T, 2048, f2Parts, 1024, nullptr,
            2048, 0, 0, 0, 0, pSD);
        ln_fused<<<3072, 256, 0, stream>>>(h, f2Parts, pSD, barena + OFF_BF2 + l * D,
                                           hbf, barena + OFF_G2 + l * D, barena + OFF_B2N + l * D);
    }
    head_kernel<<<out_size, 256, 0, stream>>>(flag, h, barena, nePtr, naPtr, d_out);
}

// Round 5
// 1560.771 us; speedup vs baseline: 1.0973x; 1.0973x over previous
//
#include <hip/hip_runtime.h>
#include <cstdint>

typedef unsigned short u16;
typedef __bf16  bf16x8 __attribute__((ext_vector_type(8)));
typedef float   f32x4  __attribute__((ext_vector_type(4)));

#define S_LEN 3072
#define DMODEL 1024

__device__ __forceinline__ float bf2f(u16 u){ return __uint_as_float(((unsigned)u) << 16); }
__device__ __forceinline__ u16 f2bf(float f){
    unsigned u = __float_as_uint(f);
    return (u16)((u + 0x7fffu + ((u >> 16) & 1u)) >> 16);
}
// mode-aware element fetch -> bf16 bits (mode 0: bf16 input; mode 1: fp32 input)
__device__ __forceinline__ u16 cvld(const void* p, long i, int mode){
    return mode ? f2bf(((const float*)p)[i]) : ((const u16*)p)[i];
}

__device__ __forceinline__ void async16(const void* g, void* l){
    __builtin_amdgcn_global_load_lds(
        (const __attribute__((address_space(1))) unsigned int*)g,
        (__attribute__((address_space(3))) unsigned int*)l, 16, 0, 0);
}

// ---------------------------------------------------------------------------
// dtype sniffer (proven): flag[0]=1 if inputs are fp32, 0 if bf16; flag[1]=0.
// ---------------------------------------------------------------------------
__global__ void sniff_kernel(const u16* __restrict__ x, int* __restrict__ flag)
{
    __shared__ int r[256];
    int tid = threadIdx.x, w = 0;
    for (int j = tid; j < 4096; j += 256){
        int e = (x[j] >> 7) & 0xFF;
        if (e < 90 || e > 140) w++;
    }
    r[tid] = w; __syncthreads();
    for (int s = 128; s > 0; s >>= 1){ if (tid < s) r[tid] += r[tid + s]; __syncthreads(); }
    if (tid == 0){ flag[0] = (r[0] > 256) ? 1 : 0; flag[1] = 0; }
}

// ---------------------------------------------------------------------------
// NT GEMM 128x128 (m97 structure), with split-K fp32-partial mode.
// ---------------------------------------------------------------------------
template<int SPLIT, bool SPLITN>
__global__ __launch_bounds__(256)
void gemm_nt(const u16* __restrict__ A, int lda,
             const u16* __restrict__ B, int ldb,
             void* __restrict__ Cv, int ldc,
             const u16* __restrict__ bias,
             int K, int splitRows,
             long aBS, long bBS, long cBS, long pStride)
{
    __shared__ __align__(16) u16 Abuf[128 * 64];
    __shared__ __align__(16) u16 Bbuf[128 * 64];
    const int tid  = threadIdx.x;
    const int lane = tid & 63, wid = tid >> 6;
    const int wm = wid >> 1, wn = wid & 1;
    const int quad = lane >> 4, lr = lane & 15;

    const int z   = blockIdx.z;
    const int bat = z / SPLIT;
    const int sp  = z % SPLIT;
    const int kLen = K / SPLIT;

    A += (long)bat * aBS + (long)blockIdx.x * 128 * lda + (long)sp * kLen;
    B += (long)bat * bBS + (long)blockIdx.y * 128 * ldb + (long)sp * kLen;

    f32x4 zero = {0.f, 0.f, 0.f, 0.f};
    f32x4 acc[4][4];
#pragma unroll
    for (int i = 0; i < 4; i++)
#pragma unroll
        for (int j = 0; j < 4; j++) acc[i][j] = zero;

    int um[4], ukq[4];
#pragma unroll
    for (int i = 0; i < 4; i++){
        int u = i * 256 + tid;
        um[i]  = u >> 3;
        ukq[i] = u & 7;
    }

    const int kTiles = kLen >> 6;
    for (int kt = 0; kt < kTiles; ++kt){
        const int k0 = kt << 6;
        __syncthreads();
#pragma unroll
        for (int i = 0; i < 4; i++)
            async16(A + (long)um[i] * lda + k0 + ukq[i] * 8, Abuf + (i * 256 + tid) * 8);
#pragma unroll
        for (int i = 0; i < 4; i++)
            async16(B + (long)um[i] * ldb + k0 + ukq[i] * 8, Bbuf + (i * 256 + tid) * 8);
        __syncthreads();
#pragma unroll
        for (int ks = 0; ks < 2; ++ks){
            bf16x8 af[4], bfg[4];
#pragma unroll
            for (int t = 0; t < 4; t++){
                int m  = wm * 64 + t * 16 + lr;
                af[t]  = *(const bf16x8*)(Abuf + (m * 8 + ks * 4 + quad) * 8);
                int n  = wn * 64 + t * 16 + lr;
                bfg[t] = *(const bf16x8*)(Bbuf + (n * 8 + ks * 4 + quad) * 8);
            }
#pragma unroll
            for (int mt = 0; mt < 4; mt++)
#pragma unroll
                for (int nt = 0; nt < 4; nt++)
                    acc[mt][nt] = __builtin_amdgcn_mfma_f32_16x16x32_bf16(
                        af[mt], bfg[nt], acc[mt][nt], 0, 0, 0);
        }
    }

    const int rowBase = blockIdx.x * 128 + wm * 64;
    const int colBase = blockIdx.y * 128 + wn * 64;
#pragma unroll
    for (int mt = 0; mt < 4; ++mt){
#pragma unroll
        for (int nt = 0; nt < 4; ++nt){
            const int col = colBase + nt * 16 + lr;
            float bv2 = (SPLIT == 1 && bias) ? bf2f(bias[col]) : 0.f;
#pragma unroll
            for (int r = 0; r < 4; r++){
                int row = rowBase + mt * 16 + quad * 4 + r;
                float v = acc[mt][nt][r] + bv2;
                if (SPLIT == 1){
                    long idx;
                    if (SPLITN) idx = ((long)(col >> 10) * splitRows + row) * DMODEL + (col & (DMODEL - 1));
                    else        idx = (long)row * ldc + col;
                    ((u16*)Cv)[(long)bat * cBS + idx] = f2bf(v);
                } else {
                    float* P = (float*)Cv + (long)sp * pStride + (long)bat * cBS;
                    P[(long)row * ldc + col] = v;
                }
            }
        }
    }
}

// ---------------------------------------------------------------------------
// NT GEMM 64x128 tile: 4 waves side-by-side in N, each 64x32 (4mt x 2nt).
// Same staging scheme; 24 KB LDS; for M- or N-starved shapes.
// ---------------------------------------------------------------------------
template<bool RELU, bool SPLITN>
__global__ __launch_bounds__(256)
void gemm64(const u16* __restrict__ A, int lda,
            const u16* __restrict__ B, int ldb,
            u16* __restrict__ C, int ldc,
            const u16* __restrict__ bias,
            int K, int splitRows,
            long aBS, long bBS, long cBS)
{
    __shared__ __align__(16) u16 Abuf[64 * 64];
    __shared__ __align__(16) u16 Bbuf[128 * 64];
    const int tid  = threadIdx.x;
    const int lane = tid & 63, wid = tid >> 6;
    const int quad = lane >> 4, lr = lane & 15;

    const int bat = blockIdx.z;
    A += (long)bat * aBS + (long)blockIdx.x * 64 * lda;
    B += (long)bat * bBS + (long)blockIdx.y * 128 * ldb;

    f32x4 zero = {0.f, 0.f, 0.f, 0.f};
    f32x4 acc[4][2];
#pragma unroll
    for (int i = 0; i < 4; i++){ acc[i][0] = zero; acc[i][1] = zero; }

    const int kTiles = K >> 6;
    for (int kt = 0; kt < kTiles; ++kt){
        const int k0 = kt << 6;
        __syncthreads();
#pragma unroll
        for (int i = 0; i < 2; i++){
            int u = i * 256 + tid;
            async16(A + (long)(u >> 3) * lda + k0 + (u & 7) * 8, Abuf + u * 8);
        }
#pragma unroll
        for (int i = 0; i < 4; i++){
            int u = i * 256 + tid;
            async16(B + (long)(u >> 3) * ldb + k0 + (u & 7) * 8, Bbuf + u * 8);
        }
        __syncthreads();
#pragma unroll
        for (int ks = 0; ks < 2; ++ks){
            bf16x8 af[4], bfg[2];
#pragma unroll
            for (int t = 0; t < 4; t++){
                int m  = t * 16 + lr;
                af[t]  = *(const bf16x8*)(Abuf + (m * 8 + ks * 4 + quad) * 8);
            }
#pragma unroll
            for (int t = 0; t < 2; t++){
                int n  = wid * 32 + t * 16 + lr;
                bfg[t] = *(const bf16x8*)(Bbuf + (n * 8 + ks * 4 + quad) * 8);
            }
#pragma unroll
            for (int mt = 0; mt < 4; mt++)
#pragma unroll
                for (int nt = 0; nt < 2; nt++)
                    acc[mt][nt] = __builtin_amdgcn_mfma_f32_16x16x32_bf16(
                        af[mt], bfg[nt], acc[mt][nt], 0, 0, 0);
        }
    }

    const int rowBase = blockIdx.x * 64;
    const int colBase = blockIdx.y * 128 + wid * 32;
#pragma unroll
    for (int mt = 0; mt < 4; ++mt){
#pragma unroll
        for (int nt = 0; nt < 2; ++nt){
            const int col = colBase + nt * 16 + lr;
            float bv2 = bias ? bf2f(bias[col]) : 0.f;
#pragma unroll
            for (int r = 0; r < 4; r++){
                int row = rowBase + mt * 16 + quad * 4 + r;
                float v = acc[mt][nt][r] + bv2;
                if (RELU) v = fmaxf(v, 0.f);
                long idx;
                if (SPLITN) idx = ((long)(col >> 10) * splitRows + row) * DMODEL + (col & (DMODEL - 1));
                else        idx = (long)row * ldc + col;
                C[(long)bat * cBS + idx] = f2bf(v);
            }
        }
    }
}

// ---------------------------------------------------------------------------
// merged per-layer weight prep: all transposes + Wq|Wk|Wv copy, one launch.
// grid.x = 7680 blocks, block (32,8).
//   [0,1024):    Wo   (1024x1024) -> WoT
//   [1024,3072): Wf1  (1024x2048) -> Wf1T
//   [3072,5120): Wf2  (2048x1024) -> Wf2T
//   [5120,6144): Wh   4x(1024x256) -> WhT slabs
//   [6144,7680): copy Wq|Wk|Wv -> Wcat (2048 elems/block)
// ---------------------------------------------------------------------------
__global__ __launch_bounds__(256)
void wprep(const int* __restrict__ flag, int l,
           const void* Wo, const void* Wf1, const void* Wf2, const void* Wh,
           const void* Wq, const void* Wk, const void* Wv,
           u16* __restrict__ WoT, u16* __restrict__ Wf1T,
           u16* __restrict__ Wf2T, u16* __restrict__ WhT,
           u16* __restrict__ Wcat)
{
    const int mode = *flag;
    const int z = blockIdx.x;
    const int tx = threadIdx.x, ty = threadIdx.y;

    if (z >= 6144){
        // copy region
        int t = ty * 32 + tx;
        long base = (long)(z - 6144) * 2048;
#pragma unroll
        for (int j = 0; j < 8; j++){
            long g = base + j * 256 + t;           // < 3*1048576
            int slab = (int)(g >> 20);
            long r = g & 1048575;
            const void* src = (slab == 0) ? Wq : (slab == 1) ? Wk : Wv;
            Wcat[g] = cvld(src, (long)l * 1048576 + r, mode);
        }
        return;
    }

    const void* in; u16* out; long ib; int R, C, rb, cb;
    if (z < 1024){
        in = Wo; out = WoT; ib = (long)l * 1048576; R = 1024; C = 1024;
        cb = z & 31; rb = z >> 5;
    } else if (z < 3072){
        int t = z - 1024;
        in = Wf1; out = Wf1T; ib = (long)l * 2097152; R = 1024; C = 2048;
        cb = t & 63; rb = t >> 6;
    } else if (z < 5120){
        int t = z - 3072;
        in = Wf2; out = Wf2T; ib = (long)l * 2097152; R = 2048; C = 1024;
        cb = t & 31; rb = t >> 5;
    } else {
        int t = z - 5120;
        int a = t >> 8, u = t & 255;
        in = Wh; out = WhT + (long)a * 262144;
        ib = (long)l * 1048576 + (long)a * 262144; R = 1024; C = 256;
        cb = u & 7; rb = u >> 3;
    }

    __shared__ u16 tbuf[32][34];
    int r0 = rb * 32, c0 = cb * 32;
#pragma unroll
    for (int j = 0; j < 4; j++){
        int r = r0 + ty + j * 8;
        tbuf[ty + j * 8][tx] = cvld(in, ib + (long)r * C + c0 + tx, mode);
    }
    __syncthreads();
#pragma unroll
    for (int j = 0; j < 4; j++){
        int c = c0 + ty + j * 8;
        out[(long)c * R + r0 + tx] = tbuf[tx][ty + j * 8];
    }
}

// ---------------------------------------------------------------------------
// mode-aware tiled transpose (kept for Vh^T)
// ---------------------------------------------------------------------------
__global__ __launch_bounds__(256)
void transpose_cvt(const int* __restrict__ flag, const void* __restrict__ in, long srcOff,
                   u16* __restrict__ out, int R, int C, long inB, long outB)
{
    __shared__ u16 t[32][34];
    const int mode = *flag;
    const long ib = srcOff + (long)blockIdx.z * inB;
    u16*       op = out + (long)blockIdx.z * outB;
    int c0 = blockIdx.x * 32, r0 = blockIdx.y * 32;
    int tx = threadIdx.x, ty = threadIdx.y;
#pragma unroll
    for (int j = 0; j < 4; j++){
        int r = r0 + ty + j * 8;
        t[ty + j * 8][tx] = cvld(in, ib + (long)r * C + c0 + tx, mode);
    }
    __syncthreads();
#pragma unroll
    for (int j = 0; j < 4; j++){
        int c = c0 + ty + j * 8;
        op[(long)c * R + r0 + tx] = t[tx][ty + j * 8];
    }
}

__global__ __launch_bounds__(256)
void init_h(const int* __restrict__ flag, const void* __restrict__ hin,
            float* __restrict__ h, u16* __restrict__ hbf)
{
    const int mode = *flag;
    long i = (long)blockIdx.x * 256 + threadIdx.x;
    u16 u = cvld(hin, i, mode);
    h[i]   = bf2f(u);
    hbf[i] = u;
}

// bias arena layout (elements)
#define OFF_BQKV 0
#define OFF_BH   12288
#define OFF_BO   16384
#define OFF_BF1  20480
#define OFF_BF2  28672
#define OFF_G1   32768
#define OFF_B1N  36864
#define OFF_G2   40960
#define OFF_B2N  45056
#define OFF_WHD  49152
#define OFF_BHD  53248
#define BIAS_TOT 53252

__global__ __launch_bounds__(256)
void cvt_biases(const int* __restrict__ flag,
                const void* bq, const void* bk, const void* bv, const void* bh,
                const void* bo, const void* bf1, const void* bf2,
                const void* g1, const void* b1n, const void* g2, const void* b2n,
                const void* whd, const void* bhd, u16* __restrict__ A)
{
    int i = blockIdx.x * 256 + threadIdx.x;
    if (i >= BIAS_TOT) return;
    const int mode = *flag;
    u16 v;
    if (i < OFF_BH){
        int l = i / 3072, r = i % 3072;
        const void* p = (r < 1024) ? bq : (r < 2048) ? bk : bv;
        v = cvld(p, (long)l * 1024 + (r & 1023), mode);
    }
    else if (i < OFF_BO)  v = cvld(bh,  i - OFF_BH, mode);
    else if (i < OFF_BF1) v = cvld(bo,  i - OFF_BO, mode);
    else if (i < OFF_BF2) v = cvld(bf1, i - OFF_BF1, mode);
    else if (i < OFF_G1)  v = cvld(bf2, i - OFF_BF2, mode);
    else if (i < OFF_B1N) v = cvld(g1,  i - OFF_G1, mode);
    else if (i < OFF_G2)  v = cvld(b1n, i - OFF_B1N, mode);
    else if (i < OFF_B2N) v = cvld(g2,  i - OFF_G2, mode);
    else if (i < OFF_WHD) v = cvld(b2n, i - OFF_B2N, mode);
    else if (i < OFF_BHD) v = cvld(whd, i - OFF_WHD, mode);
    else                  v = cvld(bhd, i - OFF_BHD, mode);
    A[i] = v;
}

// combined QKV+head bias: bqkvh[z*1024+n] = sum_d b_z[d]*WhT[n,d] + bh[l,n]
__global__ __launch_bounds__(256)
void bias_combine(const u16* __restrict__ arena, const u16* __restrict__ WhT,
                  int l, u16* __restrict__ bqkvh)
{
    int i = blockIdx.x * 256 + threadIdx.x;   // < 3072
    int z = i >> 10, n = i & 1023;
    const u16* bz = arena + OFF_BQKV + l * 3072 + z * 1024;
    const u16* wr = WhT + (long)n * 1024;
    float s = bf2f(arena[OFF_BH + l * 1024 + n]);
    for (int d = 0; d < 1024; d += 8){
        bf16x8 w = *(const bf16x8*)(wr + d);
        bf16x8 b = *(const bf16x8*)(bz + d);
#pragma unroll
        for (int j = 0; j < 8; j++) s += (float)w[j] * (float)b[j];
    }
    bqkvh[i] = f2bf(s);
}

__device__ __forceinline__ float blockSum(float v, float* red){
    int lane = threadIdx.x & 63, wid = threadIdx.x >> 6;
#pragma unroll
    for (int o = 32; o > 0; o >>= 1) v += __shfl_down(v, o, 64);
    __syncthreads();
    if (lane == 0) red[wid] = v;
    __syncthreads();
    return red[0] + red[1] + red[2] + red[3];
}
__device__ __forceinline__ float blockMax(float v, float* red){
    int lane = threadIdx.x & 63, wid = threadIdx.x >> 6;
#pragma unroll
    for (int o = 32; o > 0; o >>= 1) v = fmaxf(v, __shfl_down(v, o, 64));
    __syncthreads();
    if (lane == 0) red[wid] = v;
    __syncthreads();
    return fmaxf(fmaxf(red[0], red[1]), fmaxf(red[2], red[3]));
}

// h = LN(h + bias + sum_{s<4} parts[s]) * g + b ; fp32 h in place, bf16 copy
__global__ __launch_bounds__(256)
void ln_fused(float* __restrict__ h, const float* __restrict__ parts, long pStride,
              const u16* __restrict__ bias, u16* __restrict__ hbf,
              const u16* __restrict__ g, const u16* __restrict__ b)
{
    __shared__ float red[4];
    long base = (long)blockIdx.x * DMODEL;
    int tid = threadIdx.x;
    float v[4];
    float s = 0.f;
#pragma unroll
    for (int j = 0; j < 4; j++){
        int c = tid + j * 256;
        float x = bf2f(bias[c]);
#pragma unroll
        for (int sp = 0; sp < 4; sp++) x += parts[(long)sp * pStride + base + c];
        float r = h[base + c] + x;
        v[j] = r; s += r;
    }
    float mu = blockSum(s, red) * (1.f / DMODEL);
    float s2 = 0.f;
#pragma unroll
    for (int j = 0; j < 4; j++){ float d = v[j] - mu; s2 += d * d; }
    float var = blockSum(s2, red) * (1.f / DMODEL);
    float inv = rsqrtf(var + 1e-5f);
#pragma unroll
    for (int j = 0; j < 4; j++){
        int c = tid + j * 256;
        float y = (v[j] - mu) * inv * bf2f(g[c]) + bf2f(b[c]);
        h[base + c]   = y;
        hbf[base + c] = f2bf(y);
    }
}

// sum nsplit fp32 partials -> bf16 (4 elems/thread)
__global__ __launch_bounds__(256)
void reduce_ctx(const float* __restrict__ parts, long pStride, int nsplit,
                u16* __restrict__ out)
{
    long i0 = ((long)blockIdx.x * 256 + threadIdx.x) * 4;
#pragma unroll
    for (int j = 0; j < 4; j++){
        long i = i0 + j;
        float s = 0.f;
        for (int sp = 0; sp < nsplit; sp++) s += parts[(long)sp * pStride + i];
        out[i] = f2bf(s);
    }
}

// in-place row softmax (bf16, row length S_LEN), scale 1/sqrt(DK)
__global__ __launch_bounds__(256)
void softmax_kernel(u16* __restrict__ P)
{
    __shared__ float red[4];
    u16* row = P + ((long)blockIdx.y * S_LEN + blockIdx.x) * S_LEN;
    int tid = threadIdx.x;
    const float scale = 0.0625f;
    float x[12];
    float m = -1e30f;
#pragma unroll
    for (int j = 0; j < 12; j++){
        x[j] = bf2f(row[tid + j * 256]) * scale;
        m = fmaxf(m, x[j]);
    }
    m = blockMax(m, red);
    float s = 0.f;
#pragma unroll
    for (int j = 0; j < 12; j++){ x[j] = __expf(x[j] - m); s += x[j]; }
    s = blockSum(s, red);
    float inv = 1.f / s;
#pragma unroll
    for (int j = 0; j < 12; j++) row[tid + j * 256] = f2bf(x[j] * inv);
}

__global__ __launch_bounds__(256)
void head_kernel(const int* __restrict__ flag, const float* __restrict__ h,
                 const u16* __restrict__ arena, const int* __restrict__ nePtr,
                 const int* __restrict__ naPtr, void* __restrict__ outp)
{
    __shared__ float red[4];
    int o = blockIdx.x;
    int ne = *nePtr, na = *naPtr;
    int widx, row;
    if (o < 3 * na){ widx = o / na; row = ne + o % na; }
    else           { widx = 3;      row = o - 3 * na; }
    int tid = threadIdx.x;
    const float* hr = h + (long)row * DMODEL;
    const u16*   w  = arena + OFF_WHD + widx * DMODEL;
    float s = 0.f;
#pragma unroll
    for (int j = 0; j < 4; j++){ int c = tid + j * 256; s += hr[c] * bf2f(w[c]); }
    s = blockSum(s, red);
    if (tid == 0){
        float r = s + bf2f(arena[OFF_BHD + widx]);
        if (*flag) ((float*)outp)[o] = r;
        else       ((u16*)outp)[o]   = f2bf(r);
    }
}

// ---------------------------------------------------------------------------
extern "C" void kernel_launch(void* const* d_in, const int* in_sizes, int n_in,
                              void* d_out, int out_size, void* d_ws, size_t ws_size,
                              hipStream_t stream)
{
    const void* hidden = d_in[0];
    const void* Wq  = d_in[1];  const void* bq  = d_in[2];
    const void* Wk  = d_in[3];  const void* bk  = d_in[4];
    const void* Wv  = d_in[5];  const void* bv  = d_in[6];
    const void* Wh  = d_in[7];  const void* bh  = d_in[8];
    const void* Wo  = d_in[9];  const void* bo  = d_in[10];
    const void* g1  = d_in[11]; const void* b1n = d_in[12];
    const void* g2  = d_in[13]; const void* b2n = d_in[14];
    const void* Wf1 = d_in[15]; const void* bf1 = d_in[16];
    const void* Wf2 = d_in[17]; const void* bf2 = d_in[18];
    const void* Whd = d_in[19]; const void* bhd = d_in[20];
    const int* nePtr = (const int*)d_in[21];
    const int* naPtr = (const int*)d_in[22];

    const long D = 1024, S = 3072, L = 4, DK = 256;

    char* ws = (char*)d_ws;
    size_t off = 0;
    auto alloc = [&](size_t bytes)->char*{
        char* p = ws + off;
        off = (off + bytes + 255) & ~(size_t)255;
        return p;
    };
    int*  flag   = (int*)alloc(256);
    u16*  barena = (u16*)alloc(BIAS_TOT * 2);
    u16*  bqkvh  = (u16*)alloc(3 * D * 2);
    u16*  WhT    = (u16*)alloc(D * D * 2);
    u16*  WqkvhT = (u16*)alloc(3 * D * D * 2);     // combined (Wz@Wh)^T (3072x1024)
    u16*  WoT    = (u16*)alloc(D * D * 2);
    u16*  Wf1T   = (u16*)alloc(2 * D * D * 2);
    u16*  Wf2T   = (u16*)alloc(2 * D * D * 2);
    float* h     = (float*)alloc(S * D * 4);
    u16*  hbf    = (u16*)alloc(S * D * 2);
    u16*  qkvh   = (u16*)alloc(3 * S * D * 2);     // [Qh;Kh;Vh] stacked
    char* regionA = alloc(2 * S * D * 2);          // vhT (DxS) + ctx (SxD)
    size_t baseEnd = off;

    size_t reg4 = (size_t)4 * S * S * 2;                       // 75.5 MB
    size_t reg1 = (size_t)4 * S * D * 4 + (size_t)S * D * 2;   // >= woParts/f2Parts/ffn1/Wcat
    int HBv = (ws_size >= baseEnd + reg4 + 4096) ? 4 : 1;
    char* regionB = alloc(HBv == 4 ? reg4 : reg1);
    size_t endB = off;
    size_t cp1 = (size_t)S * D * 4;
    int ctxSplit = (ws_size >= endB + 4 * cp1 + 4096) ? 4
                 : (ws_size >= endB + 2 * cp1 + 4096) ? 2 : 1;
    float* ctxParts = (float*)alloc(ctxSplit > 1 ? (size_t)ctxSplit * cp1 : 0);

    u16* vhT     = (u16*)regionA;                  // (D x S)
    u16* ctx     = (u16*)regionA + D * S;          // (S x D)
    u16* scoresP = (u16*)regionB;
    u16* Wcat    = (u16*)regionB;                  // [Wq;Wk;Wv] (prep phase)
    float* woParts = (float*)regionB;              // 4 x (S*D) fp32 (scores dead)
    u16* ffn1    = (u16*)regionB;                  // (S x 2048) bf16
    float* f2Parts = (float*)(regionB + (size_t)S * 2 * D * 2);

    const long pSD = S * D;

    dim3 tb(32, 8);
    sniff_kernel<<<1, 256, 0, stream>>>((const u16*)hidden, flag);
    cvt_biases<<<(BIAS_TOT + 255) / 256, 256, 0, stream>>>(
        flag, bq, bk, bv, bh, bo, bf1, bf2, g1, b1n, g2, b2n, Whd, bhd, barena);
    init_h<<<(int)(S * D / 256), 256, 0, stream>>>(flag, hidden, h, hbf);

    for (int l = 0; l < L; ++l){
        // ---- merged weight prep (1 launch) ----
        wprep<<<7680, tb, 0, stream>>>(flag, l, Wo, Wf1, Wf2, Wh, Wq, Wk, Wv,
                                       WoT, Wf1T, Wf2T, WhT, Wcat);
        // combined weights: WqkvhT[z*1024+n, c] = sum_d WhT[n,d] * Wcat[z][c,d]
        gemm64<false, false><<<dim3(16, 8, 3), 256, 0, stream>>>(
            WhT, 1024, Wcat, 1024, WqkvhT, 1024, nullptr,
            1024, 0, 0, (long)D * D, (long)D * D);
        bias_combine<<<12, 256, 0, stream>>>(barena, WhT, l, bqkvh);

        // ---- fused QKV+head projection (64-row tiles: 1152 blocks) ----
        gemm64<false, true><<<dim3(48, 24, 1), 256, 0, stream>>>(
            hbf, 1024, WqkvhT, 1024, qkvh, 0, bqkvh,
            1024, (int)S, 0, 0, 0);
        transpose_cvt<<<dim3(32, 96, 1), tb, 0, stream>>>(flag + 1, qkvh, 2 * S * D, vhT, (int)S, (int)D, 0, 0);

        // ---- attention ----
        for (int h0 = 0; h0 < 4; h0 += HBv){
            gemm_nt<1, false><<<dim3(24, 24, HBv), 256, 0, stream>>>(
                qkvh + h0 * DK, 1024, qkvh + S * D + h0 * DK, 1024,
                scoresP, (int)S, nullptr, (int)DK, 0, DK, DK, (long)S * S, 0);
            softmax_kernel<<<dim3(3072, HBv), 256, 0, stream>>>(scoresP);
            if (ctxSplit == 4)
                gemm_nt<4, false><<<dim3(24, 2, HBv * 4), 256, 0, stream>>>(
                    scoresP, (int)S, vhT + (long)h0 * DK * S, (int)S,
                    ctxParts + h0 * DK, 1024, nullptr, (int)S, 0,
                    (long)S * S, (long)DK * S, DK, pSD);
            else if (ctxSplit == 2)
                gemm_nt<2, false><<<dim3(24, 2, HBv * 2), 256, 0, stream>>>(
                    scoresP, (int)S, vhT + (long)h0 * DK * S, (int)S,
                    ctxParts + h0 * DK, 1024, nullptr, (int)S, 0,
                    (long)S * S, (long)DK * S, DK, pSD);
            else
                gemm_nt<1, false><<<dim3(24, 2, HBv), 256, 0, stream>>>(
                    scoresP, (int)S, vhT + (long)h0 * DK * S, (int)S,
                    ctx + h0 * DK, 1024, nullptr, (int)S, 0,
                    (long)S * S, (long)DK * S, DK, 0);
        }
        if (ctxSplit > 1)
            reduce_ctx<<<3072, 256, 0, stream>>>(ctxParts, pSD, ctxSplit, ctx);

        // ---- attn_out: split-K=4; reduce fused into LN ----
        gemm_nt<4, false><<<dim3(24, 8, 4), 256, 0, stream>>>(
            ctx, 1024, WoT, 1024, woParts, 1024, nullptr,
            1024, 0, 0, 0, 0, pSD);
        ln_fused<<<3072, 256, 0, stream>>>(h, woParts, pSD, barena + OFF_BO + l * D,
                                           hbf, barena + OFF_G1 + l * D, barena + OFF_B1N + l * D);
        // ---- FFN1: single gemm64, bias+ReLU fused (768 blocks) ----
        gemm64<true, false><<<dim3(48, 16, 1), 256, 0, stream>>>(
            hbf, 1024, Wf1T, 1024, ffn1, 2048, barena + OFF_BF1 + l * 2 * D,
            1024, 0, 0, 0, 0);
        // ---- FFN2: split-K=4; reduce fused into LN ----
        gemm_nt<4, false><<<dim3(24, 8, 4), 256, 0, stream>>>(
            ffn1, 2048, Wf2T, 2048, f2Parts, 1024, nullptr,
            2048, 0, 0, 0, 0, pSD);
        ln_fused<<<3072, 256, 0, stream>>>(h, f2Parts, pSD, barena + OFF_BF2 + l * D,
                                           hbf, barena + OFF_G2 + l * D, barena + OFF_B2N + l * D);
    }
    head_kernel<<<out_size, 256, 0, stream>>>(flag, h, barena, nePtr, naPtr, d_out);
}

// Round 6
// 1382.081 us; speedup vs baseline: 1.2391x; 1.1293x over previous
//
#include <hip/hip_runtime.h>
#include <cstdint>

typedef unsigned short u16;
typedef __bf16  bf16x8 __attribute__((ext_vector_type(8)));
typedef float   f32x4  __attribute__((ext_vector_type(4)));
typedef unsigned short u16x4 __attribute__((ext_vector_type(4)));

#define S_LEN 3072
#define DMODEL 1024

__device__ __forceinline__ float bf2f(u16 u){ return __uint_as_float(((unsigned)u) << 16); }
__device__ __forceinline__ u16 f2bf(float f){
    unsigned u = __float_as_uint(f);
    return (u16)((u + 0x7fffu + ((u >> 16) & 1u)) >> 16);
}
// mode-aware element fetch -> bf16 bits (mode 0: bf16 input; mode 1: fp32 input)
__device__ __forceinline__ u16 cvld(const void* p, long i, int mode){
    return mode ? f2bf(((const float*)p)[i]) : ((const u16*)p)[i];
}

__device__ __forceinline__ void async16(const void* g, void* l){
    __builtin_amdgcn_global_load_lds(
        (const __attribute__((address_space(1))) unsigned int*)g,
        (__attribute__((address_space(3))) unsigned int*)l, 16, 0, 0);
}

// ---------------------------------------------------------------------------
// dtype sniffer (proven): flag[0]=1 if inputs are fp32, 0 if bf16; flag[1]=0.
// ---------------------------------------------------------------------------
__global__ void sniff_kernel(const u16* __restrict__ x, int* __restrict__ flag)
{
    __shared__ int r[256];
    int tid = threadIdx.x, w = 0;
    for (int j = tid; j < 4096; j += 256){
        int e = (x[j] >> 7) & 0xFF;
        if (e < 90 || e > 140) w++;
    }
    r[tid] = w; __syncthreads();
    for (int s = 128; s > 0; s >>= 1){ if (tid < s) r[tid] += r[tid + s]; __syncthreads(); }
    if (tid == 0){ flag[0] = (r[0] > 256) ? 1 : 0; flag[1] = 0; }
}

// ---------------------------------------------------------------------------
// Scores GEMM 128x128 (m97 structure) with fused max-free-softmax epilogue:
// writes P~ = exp(score*1/16) in bf16 and atomically accumulates row sums.
// z = head; A/B are Qh/Kh slices (head offset via aBS/bBS), C via cBS.
// ---------------------------------------------------------------------------
__global__ __launch_bounds__(256)
void gemm_scores(const u16* __restrict__ A, int lda,
                 const u16* __restrict__ B, int ldb,
                 u16* __restrict__ C, int ldc,
                 float* __restrict__ rowSums,
                 int K, long aBS, long bBS, long cBS)
{
    __shared__ __align__(16) u16 Abuf[128 * 64];
    __shared__ __align__(16) u16 Bbuf[128 * 64];
    const int tid  = threadIdx.x;
    const int lane = tid & 63, wid = tid >> 6;
    const int wm = wid >> 1, wn = wid & 1;
    const int quad = lane >> 4, lr = lane & 15;
    const int bat = blockIdx.z;

    A += (long)bat * aBS + (long)blockIdx.x * 128 * lda;
    B += (long)bat * bBS + (long)blockIdx.y * 128 * ldb;

    f32x4 zero = {0.f, 0.f, 0.f, 0.f};
    f32x4 acc[4][4];
#pragma unroll
    for (int i = 0; i < 4; i++)
#pragma unroll
        for (int j = 0; j < 4; j++) acc[i][j] = zero;

    int um[4], ukq[4];
#pragma unroll
    for (int i = 0; i < 4; i++){
        int u = i * 256 + tid;
        um[i]  = u >> 3;
        ukq[i] = u & 7;
    }

    const int kTiles = K >> 6;
    for (int kt = 0; kt < kTiles; ++kt){
        const int k0 = kt << 6;
        __syncthreads();
#pragma unroll
        for (int i = 0; i < 4; i++)
            async16(A + (long)um[i] * lda + k0 + ukq[i] * 8, Abuf + (i * 256 + tid) * 8);
#pragma unroll
        for (int i = 0; i < 4; i++)
            async16(B + (long)um[i] * ldb + k0 + ukq[i] * 8, Bbuf + (i * 256 + tid) * 8);
        __syncthreads();
#pragma unroll
        for (int ks = 0; ks < 2; ++ks){
            bf16x8 af[4], bfg[4];
#pragma unroll
            for (int t = 0; t < 4; t++){
                int m  = wm * 64 + t * 16 + lr;
                af[t]  = *(const bf16x8*)(Abuf + (m * 8 + ks * 4 + quad) * 8);
                int n  = wn * 64 + t * 16 + lr;
                bfg[t] = *(const bf16x8*)(Bbuf + (n * 8 + ks * 4 + quad) * 8);
            }
#pragma unroll
            for (int mt = 0; mt < 4; mt++)
#pragma unroll
                for (int nt = 0; nt < 4; nt++)
                    acc[mt][nt] = __builtin_amdgcn_mfma_f32_16x16x32_bf16(
                        af[mt], bfg[nt], acc[mt][nt], 0, 0, 0);
        }
    }

    const int rowBase = blockIdx.x * 128 + wm * 64;
    const int colBase = blockIdx.y * 128 + wn * 64;
    const float scale = 0.0625f;                 // 1/sqrt(256)
    float rsum[4][4];
#pragma unroll
    for (int mt = 0; mt < 4; mt++)
#pragma unroll
        for (int r = 0; r < 4; r++) rsum[mt][r] = 0.f;

#pragma unroll
    for (int mt = 0; mt < 4; ++mt){
#pragma unroll
        for (int nt = 0; nt < 4; ++nt){
            const int col = colBase + nt * 16 + lr;
#pragma unroll
            for (int r = 0; r < 4; r++){
                int row = rowBase + mt * 16 + quad * 4 + r;
                float e = __expf(acc[mt][nt][r] * scale);   // |arg|<~2: max-free safe
                rsum[mt][r] += e;
                C[(long)bat * cBS + (long)row * ldc + col] = f2bf(e);
            }
        }
    }
    // reduce each rsum over the 16 lr-lanes (same quad), then one atomic per row
#pragma unroll
    for (int mt = 0; mt < 4; mt++)
#pragma unroll
        for (int r = 0; r < 4; r++){
            float v = rsum[mt][r];
#pragma unroll
            for (int o = 1; o < 16; o <<= 1) v += __shfl_xor(v, o, 64);
            if (lr == 0){
                int row = rowBase + mt * 16 + quad * 4 + r;
                atomicAdd(&rowSums[(long)bat * S_LEN + row], v);
            }
        }
}

// ---------------------------------------------------------------------------
// NT GEMM 64x128 tile: 4 waves side-by-side in N, each 64x32 (4mt x 2nt).
// SPLIT>1: fp32 partials at sp*pStride + bat*cBS. SPLIT==1 modes:
//   MODE 0: plain bf16 (+bias), MODE 1: QKV scatter (Q,K natural; V transposed
//   into slab 2 as V^T, packed ushort4), MODE 2: bias+ReLU bf16.
// ---------------------------------------------------------------------------
template<int SPLIT, int MODE>
__global__ __launch_bounds__(256)
void gemm64(const u16* __restrict__ A, int lda,
            const u16* __restrict__ B, int ldb,
            void* __restrict__ Cv, int ldc,
            const u16* __restrict__ bias,
            int K, long aBS, long bBS, long cBS, long pStride)
{
    __shared__ __align__(16) u16 Abuf[64 * 64];
    __shared__ __align__(16) u16 Bbuf[128 * 64];
    const int tid  = threadIdx.x;
    const int lane = tid & 63, wid = tid >> 6;
    const int quad = lane >> 4, lr = lane & 15;

    const int z   = blockIdx.z;
    const int bat = z / SPLIT;
    const int sp  = z % SPLIT;
    const int kLen = K / SPLIT;

    A += (long)bat * aBS + (long)blockIdx.x * 64 * lda + (long)sp * kLen;
    B += (long)bat * bBS + (long)blockIdx.y * 128 * ldb + (long)sp * kLen;

    f32x4 zero = {0.f, 0.f, 0.f, 0.f};
    f32x4 acc[4][2];
#pragma unroll
    for (int i = 0; i < 4; i++){ acc[i][0] = zero; acc[i][1] = zero; }

    const int kTiles = kLen >> 6;
    for (int kt = 0; kt < kTiles; ++kt){
        const int k0 = kt << 6;
        __syncthreads();
#pragma unroll
        for (int i = 0; i < 2; i++){
            int u = i * 256 + tid;
            async16(A + (long)(u >> 3) * lda + k0 + (u & 7) * 8, Abuf + u * 8);
        }
#pragma unroll
        for (int i = 0; i < 4; i++){
            int u = i * 256 + tid;
            async16(B + (long)(u >> 3) * ldb + k0 + (u & 7) * 8, Bbuf + u * 8);
        }
        __syncthreads();
#pragma unroll
        for (int ks = 0; ks < 2; ++ks){
            bf16x8 af[4], bfg[2];
#pragma unroll
            for (int t = 0; t < 4; t++){
                int m  = t * 16 + lr;
                af[t]  = *(const bf16x8*)(Abuf + (m * 8 + ks * 4 + quad) * 8);
            }
#pragma unroll
            for (int t = 0; t < 2; t++){
                int n  = wid * 32 + t * 16 + lr;
                bfg[t] = *(const bf16x8*)(Bbuf + (n * 8 + ks * 4 + quad) * 8);
            }
#pragma unroll
            for (int mt = 0; mt < 4; mt++)
#pragma unroll
                for (int nt = 0; nt < 2; nt++)
                    acc[mt][nt] = __builtin_amdgcn_mfma_f32_16x16x32_bf16(
                        af[mt], bfg[nt], acc[mt][nt], 0, 0, 0);
        }
    }

    const int rowBase = blockIdx.x * 64;
    const int colBase = blockIdx.y * 128 + wid * 32;
#pragma unroll
    for (int mt = 0; mt < 4; ++mt){
#pragma unroll
        for (int nt = 0; nt < 2; ++nt){
            const int col = colBase + nt * 16 + lr;
            const int row0 = rowBase + mt * 16 + quad * 4;
            if (SPLIT > 1){
                float* P = (float*)Cv + (long)sp * pStride + (long)bat * cBS;
#pragma unroll
                for (int r = 0; r < 4; r++)
                    P[(long)(row0 + r) * ldc + col] = acc[mt][nt][r];
            } else if (MODE == 1){
                float bv2 = bias ? bf2f(bias[col]) : 0.f;
                int slab = col >> 10, c = col & 1023;
                if (slab < 2){
#pragma unroll
                    for (int r = 0; r < 4; r++)
                        ((u16*)Cv)[((long)slab * S_LEN + row0 + r) * DMODEL + c] =
                            f2bf(acc[mt][nt][r] + bv2);
                } else {
                    u16x4 pk;
#pragma unroll
                    for (int r = 0; r < 4; r++) pk[r] = f2bf(acc[mt][nt][r] + bv2);
                    *(u16x4*)((u16*)Cv + (long)2 * S_LEN * DMODEL + (long)c * S_LEN + row0) = pk;
                }
            } else {
                float bv2 = bias ? bf2f(bias[col]) : 0.f;
#pragma unroll
                for (int r = 0; r < 4; r++){
                    float v = acc[mt][nt][r] + bv2;
                    if (MODE == 2) v = fmaxf(v, 0.f);
                    ((u16*)Cv)[(long)bat * cBS + (long)(row0 + r) * ldc + col] = f2bf(v);
                }
            }
        }
    }
}

// ---------------------------------------------------------------------------
// merged per-layer weight prep (transposes + Wq|Wk|Wv copy), one launch.
// ---------------------------------------------------------------------------
__global__ __launch_bounds__(256)
void wprep(const int* __restrict__ flag, int l,
           const void* Wo, const void* Wf1, const void* Wf2, const void* Wh,
           const void* Wq, const void* Wk, const void* Wv,
           u16* __restrict__ WoT, u16* __restrict__ Wf1T,
           u16* __restrict__ Wf2T, u16* __restrict__ WhT,
           u16* __restrict__ Wcat)
{
    const int mode = *flag;
    const int z = blockIdx.x;
    const int tx = threadIdx.x, ty = threadIdx.y;

    if (z >= 6144){
        int t = ty * 32 + tx;
        long base = (long)(z - 6144) * 2048;
#pragma unroll
        for (int j = 0; j < 8; j++){
            long g = base + j * 256 + t;
            int slab = (int)(g >> 20);
            long r = g & 1048575;
            const void* src = (slab == 0) ? Wq : (slab == 1) ? Wk : Wv;
            Wcat[g] = cvld(src, (long)l * 1048576 + r, mode);
        }
        return;
    }

    const void* in; u16* out; long ib; int R, C, rb, cb;
    if (z < 1024){
        in = Wo; out = WoT; ib = (long)l * 1048576; R = 1024; C = 1024;
        cb = z & 31; rb = z >> 5;
    } else if (z < 3072){
        int t = z - 1024;
        in = Wf1; out = Wf1T; ib = (long)l * 2097152; R = 1024; C = 2048;
        cb = t & 63; rb = t >> 6;
    } else if (z < 5120){
        int t = z - 3072;
        in = Wf2; out = Wf2T; ib = (long)l * 2097152; R = 2048; C = 1024;
        cb = t & 31; rb = t >> 5;
    } else {
        int t = z - 5120;
        int a = t >> 8, u = t & 255;
        in = Wh; out = WhT + (long)a * 262144;
        ib = (long)l * 1048576 + (long)a * 262144; R = 1024; C = 256;
        cb = u & 7; rb = u >> 3;
    }

    __shared__ u16 tbuf[32][34];
    int r0 = rb * 32, c0 = cb * 32;
#pragma unroll
    for (int j = 0; j < 4; j++){
        int r = r0 + ty + j * 8;
        tbuf[ty + j * 8][tx] = cvld(in, ib + (long)r * C + c0 + tx, mode);
    }
    __syncthreads();
#pragma unroll
    for (int j = 0; j < 4; j++){
        int c = c0 + ty + j * 8;
        out[(long)c * R + r0 + tx] = tbuf[tx][ty + j * 8];
    }
}

__global__ __launch_bounds__(256)
void init_h(const int* __restrict__ flag, const void* __restrict__ hin,
            float* __restrict__ h, u16* __restrict__ hbf)
{
    const int mode = *flag;
    long i = (long)blockIdx.x * 256 + threadIdx.x;
    u16 u = cvld(hin, i, mode);
    h[i]   = bf2f(u);
    hbf[i] = u;
}

__global__ __launch_bounds__(256)
void zero_sums(float* __restrict__ p)
{
    p[blockIdx.x * 256 + threadIdx.x] = 0.f;
}

// bias arena layout (elements)
#define OFF_BQKV 0
#define OFF_BH   12288
#define OFF_BO   16384
#define OFF_BF1  20480
#define OFF_BF2  28672
#define OFF_G1   32768
#define OFF_B1N  36864
#define OFF_G2   40960
#define OFF_B2N  45056
#define OFF_WHD  49152
#define OFF_BHD  53248
#define BIAS_TOT 53252

__global__ __launch_bounds__(256)
void cvt_biases(const int* __restrict__ flag,
                const void* bq, const void* bk, const void* bv, const void* bh,
                const void* bo, const void* bf1, const void* bf2,
                const void* g1, const void* b1n, const void* g2, const void* b2n,
                const void* whd, const void* bhd, u16* __restrict__ A)
{
    int i = blockIdx.x * 256 + threadIdx.x;
    if (i >= BIAS_TOT) return;
    const int mode = *flag;
    u16 v;
    if (i < OFF_BH){
        int l = i / 3072, r = i % 3072;
        const void* p = (r < 1024) ? bq : (r < 2048) ? bk : bv;
        v = cvld(p, (long)l * 1024 + (r & 1023), mode);
    }
    else if (i < OFF_BO)  v = cvld(bh,  i - OFF_BH, mode);
    else if (i < OFF_BF1) v = cvld(bo,  i - OFF_BO, mode);
    else if (i < OFF_BF2) v = cvld(bf1, i - OFF_BF1, mode);
    else if (i < OFF_G1)  v = cvld(bf2, i - OFF_BF2, mode);
    else if (i < OFF_B1N) v = cvld(g1,  i - OFF_G1, mode);
    else if (i < OFF_G2)  v = cvld(b1n, i - OFF_B1N, mode);
    else if (i < OFF_B2N) v = cvld(g2,  i - OFF_G2, mode);
    else if (i < OFF_WHD) v = cvld(b2n, i - OFF_B2N, mode);
    else if (i < OFF_BHD) v = cvld(whd, i - OFF_WHD, mode);
    else                  v = cvld(bhd, i - OFF_BHD, mode);
    A[i] = v;
}

// combined QKV+head bias: bqkvh[z*1024+n] = sum_d b_z[d]*WhT[n,d] + bh[l,n]
__global__ __launch_bounds__(256)
void bias_combine(const u16* __restrict__ arena, const u16* __restrict__ WhT,
                  int l, u16* __restrict__ bqkvh)
{
    int i = blockIdx.x * 256 + threadIdx.x;   // < 3072
    int z = i >> 10, n = i & 1023;
    const u16* bz = arena + OFF_BQKV + l * 3072 + z * 1024;
    const u16* wr = WhT + (long)n * 1024;
    float s = bf2f(arena[OFF_BH + l * 1024 + n]);
    for (int d = 0; d < 1024; d += 8){
        bf16x8 w = *(const bf16x8*)(wr + d);
        bf16x8 b = *(const bf16x8*)(bz + d);
#pragma unroll
        for (int j = 0; j < 8; j++) s += (float)w[j] * (float)b[j];
    }
    bqkvh[i] = f2bf(s);
}

__device__ __forceinline__ float blockSum(float v, float* red){
    int lane = threadIdx.x & 63, wid = threadIdx.x >> 6;
#pragma unroll
    for (int o = 32; o > 0; o >>= 1) v += __shfl_down(v, o, 64);
    __syncthreads();
    if (lane == 0) red[wid] = v;
    __syncthreads();
    return red[0] + red[1] + red[2] + red[3];
}

// h = LN(h + bias + sum_{sp<nparts} parts[sp]) * g + b
__global__ __launch_bounds__(256)
void ln_fused(float* __restrict__ h, const float* __restrict__ parts, long pStride,
              int nparts, const u16* __restrict__ bias, u16* __restrict__ hbf,
              const u16* __restrict__ g, const u16* __restrict__ b)
{
    __shared__ float red[4];
    long base = (long)blockIdx.x * DMODEL;
    int tid = threadIdx.x;
    float v[4];
    float s = 0.f;
#pragma unroll
    for (int j = 0; j < 4; j++){
        int c = tid + j * 256;
        float x = bf2f(bias[c]);
        for (int sp = 0; sp < nparts; sp++) x += parts[(long)sp * pStride + base + c];
        float r = h[base + c] + x;
        v[j] = r; s += r;
    }
    float mu = blockSum(s, red) * (1.f / DMODEL);
    float s2 = 0.f;
#pragma unroll
    for (int j = 0; j < 4; j++){ float d = v[j] - mu; s2 += d * d; }
    float var = blockSum(s2, red) * (1.f / DMODEL);
    float inv = rsqrtf(var + 1e-5f);
#pragma unroll
    for (int j = 0; j < 4; j++){
        int c = tid + j * 256;
        float y = (v[j] - mu) * inv * bf2f(g[c]) + bf2f(b[c]);
        h[base + c]   = y;
        hbf[base + c] = f2bf(y);
    }
}

// ctx merge: out = (sum_sp parts[sp]) / rowSums[head][row]  -> bf16
__global__ __launch_bounds__(256)
void reduce_div(const float* __restrict__ parts, long pStride, int nsplit,
                const float* __restrict__ l, u16* __restrict__ out)
{
    long i0 = ((long)blockIdx.x * 256 + threadIdx.x) * 4;
    int row  = (int)(i0 >> 10);
    int head = (int)((i0 & 1023) >> 8);
    float inv = 1.f / l[(long)head * S_LEN + row];
#pragma unroll
    for (int j = 0; j < 4; j++){
        long i = i0 + j;
        float s = 0.f;
        for (int sp = 0; sp < nsplit; sp++) s += parts[(long)sp * pStride + i];
        out[i] = f2bf(s * inv);
    }
}

__global__ __launch_bounds__(256)
void head_kernel(const int* __restrict__ flag, const float* __restrict__ h,
                 const u16* __restrict__ arena, const int* __restrict__ nePtr,
                 const int* __restrict__ naPtr, void* __restrict__ outp)
{
    __shared__ float red[4];
    int o = blockIdx.x;
    int ne = *nePtr, na = *naPtr;
    int widx, row;
    if (o < 3 * na){ widx = o / na; row = ne + o % na; }
    else           { widx = 3;      row = o - 3 * na; }
    int tid = threadIdx.x;
    const float* hr = h + (long)row * DMODEL;
    const u16*   w  = arena + OFF_WHD + widx * DMODEL;
    float s = 0.f;
#pragma unroll
    for (int j = 0; j < 4; j++){ int c = tid + j * 256; s += hr[c] * bf2f(w[c]); }
    s = blockSum(s, red);
    if (tid == 0){
        float r = s + bf2f(arena[OFF_BHD + widx]);
        if (*flag) ((float*)outp)[o] = r;
        else       ((u16*)outp)[o]   = f2bf(r);
    }
}

// ---------------------------------------------------------------------------
extern "C" void kernel_launch(void* const* d_in, const int* in_sizes, int n_in,
                              void* d_out, int out_size, void* d_ws, size_t ws_size,
                              hipStream_t stream)
{
    const void* hidden = d_in[0];
    const void* Wq  = d_in[1];  const void* bq  = d_in[2];
    const void* Wk  = d_in[3];  const void* bk  = d_in[4];
    const void* Wv  = d_in[5];  const void* bv  = d_in[6];
    const void* Wh  = d_in[7];  const void* bh  = d_in[8];
    const void* Wo  = d_in[9];  const void* bo  = d_in[10];
    const void* g1  = d_in[11]; const void* b1n = d_in[12];
    const void* g2  = d_in[13]; const void* b2n = d_in[14];
    const void* Wf1 = d_in[15]; const void* bf1 = d_in[16];
    const void* Wf2 = d_in[17]; const void* bf2 = d_in[18];
    const void* Whd = d_in[19]; const void* bhd = d_in[20];
    const int* nePtr = (const int*)d_in[21];
    const int* naPtr = (const int*)d_in[22];

    const long D = 1024, S = 3072, L = 4, DK = 256;

    char* ws = (char*)d_ws;
    size_t off = 0;
    auto alloc = [&](size_t bytes)->char*{
        char* p = ws + off;
        off = (off + bytes + 255) & ~(size_t)255;
        return p;
    };
    int*  flag   = (int*)alloc(256);
    u16*  barena = (u16*)alloc(BIAS_TOT * 2);
    u16*  bqkvh  = (u16*)alloc(3 * D * 2);
    float* rowSums = (float*)alloc(4 * S * 4);
    u16*  WhT    = (u16*)alloc(D * D * 2);
    u16*  WqkvhT = (u16*)alloc(3 * D * D * 2);     // combined (Wz@Wh)^T (3072x1024)
    u16*  WoT    = (u16*)alloc(D * D * 2);
    u16*  Wf1T   = (u16*)alloc(2 * D * D * 2);
    u16*  Wf2T   = (u16*)alloc(2 * D * D * 2);
    float* h     = (float*)alloc(S * D * 4);
    u16*  hbf    = (u16*)alloc(S * D * 2);
    u16*  qkvh   = (u16*)alloc(3 * S * D * 2);     // [Qh;Kh;V^T] (slab 2 = V^T e x s)
    u16*  ctx    = (u16*)alloc(S * D * 2);
    size_t baseEnd = off;

    size_t reg4 = (size_t)4 * S * S * 2;                       // 75.5 MB
    size_t reg1 = (size_t)S * S * 2 + (size_t)S * 2 * D * 2;   // 1-head scores + ffn1
    int HBv = (ws_size >= baseEnd + reg4 + 2 * (size_t)S * D * 4 + 4096) ? 4 : 1;
    char* regionB = alloc(HBv == 4 ? reg4 : reg1);
    size_t endB = off;
    size_t cp1 = (size_t)S * D * 4;
    int ctxSplit = (ws_size >= endB + 2 * cp1 + 4096) ? 2 : 1;
    float* ctxParts = (float*)alloc((size_t)ctxSplit * cp1);

    u16* scoresP = (u16*)regionB;
    u16* Wcat    = (u16*)regionB;                  // prep phase (scores dead)
    float* woParts = (float*)regionB;              // 2 x (S*D) fp32 (scores dead)
    u16* ffn1;                                     // (S x 2048) bf16
    float* f2Parts;                                // 2 x (S*D) fp32
    if (HBv == 4){
        ffn1    = (u16*)regionB;
        f2Parts = (float*)(regionB + (size_t)S * 2 * D * 2);
    } else {
        ffn1    = (u16*)(regionB + (size_t)S * S * 2);
        f2Parts = (float*)ctxParts;                // ctx partials dead by FFN2
    }

    const long pSD = S * D;

    dim3 tb(32, 8);
    sniff_kernel<<<1, 256, 0, stream>>>((const u16*)hidden, flag);
    cvt_biases<<<(BIAS_TOT + 255) / 256, 256, 0, stream>>>(
        flag, bq, bk, bv, bh, bo, bf1, bf2, g1, b1n, g2, b2n, Whd, bhd, barena);
    init_h<<<(int)(S * D / 256), 256, 0, stream>>>(flag, hidden, h, hbf);

    for (int l = 0; l < L; ++l){
        // ---- weight prep ----
        wprep<<<7680, tb, 0, stream>>>(flag, l, Wo, Wf1, Wf2, Wh, Wq, Wk, Wv,
                                       WoT, Wf1T, Wf2T, WhT, Wcat);
        gemm64<1, 0><<<dim3(16, 8, 3), 256, 0, stream>>>(
            WhT, 1024, Wcat, 1024, WqkvhT, 1024, nullptr,
            1024, 0, (long)D * D, (long)D * D, 0);
        bias_combine<<<12, 256, 0, stream>>>(barena, WhT, l, bqkvh);

        // ---- fused QKV+head projection; V written transposed into slab 2 ----
        gemm64<1, 1><<<dim3(48, 24, 1), 256, 0, stream>>>(
            hbf, 1024, WqkvhT, 1024, qkvh, 0, bqkvh,
            1024, 0, 0, 0, 0);

        // ---- attention: scores+exp+rowsums, then ctx (split-K) ----
        zero_sums<<<48, 256, 0, stream>>>(rowSums);
        if (HBv == 4){
            gemm_scores<<<dim3(24, 24, 4), 256, 0, stream>>>(
                qkvh, 1024, qkvh + S * D, 1024, scoresP, (int)S,
                rowSums, (int)DK, DK, DK, (long)S * S);
            gemm64<2, 0><<<dim3(48, 2, 8), 256, 0, stream>>>(
                scoresP, (int)S, qkvh + 2 * S * D, (int)S,
                ctxParts, 1024, nullptr, (int)S,
                (long)S * S, (long)DK * S, DK, pSD);
        } else {
            for (int h0 = 0; h0 < 4; ++h0){
                gemm_scores<<<dim3(24, 24, 1), 256, 0, stream>>>(
                    qkvh + h0 * DK, 1024, qkvh + S * D + h0 * DK, 1024,
                    scoresP, (int)S, rowSums + h0 * S, (int)DK, 0, 0, 0);
                gemm64<2, 0><<<dim3(48, 2, 2), 256, 0, stream>>>(
                    scoresP, (int)S, qkvh + 2 * S * D + (long)h0 * DK * S, (int)S,
                    ctxParts + h0 * DK, 1024, nullptr, (int)S,
                    0, 0, 0, ctxSplit == 2 ? pSD : 0);
            }
        }
        reduce_div<<<3072, 256, 0, stream>>>(ctxParts, pSD, ctxSplit, rowSums, ctx);

        // ---- attn_out: gemm64 split-2; reduce fused into LN ----
        gemm64<2, 0><<<dim3(48, 8, 2), 256, 0, stream>>>(
            ctx, 1024, WoT, 1024, woParts, 1024, nullptr,
            1024, 0, 0, 0, pSD);
        ln_fused<<<3072, 256, 0, stream>>>(h, woParts, pSD, 2, barena + OFF_BO + l * D,
                                           hbf, barena + OFF_G1 + l * D, barena + OFF_B1N + l * D);
        // ---- FFN1: single gemm64, bias+ReLU fused ----
        gemm64<1, 2><<<dim3(48, 16, 1), 256, 0, stream>>>(
            hbf, 1024, Wf1T, 1024, ffn1, 2048, barena + OFF_BF1 + l * 2 * D,
            1024, 0, 0, 0, 0);
        // ---- FFN2: gemm64 split-2; reduce fused into LN ----
        gemm64<2, 0><<<dim3(48, 8, 2), 256, 0, stream>>>(
            ffn1, 2048, Wf2T, 2048, f2Parts, 1024, nullptr,
            2048, 0, 0, 0, pSD);
        ln_fused<<<3072, 256, 0, stream>>>(h, f2Parts, pSD, 2, barena + OFF_BF2 + l * D,
                                           hbf, barena + OFF_G2 + l * D, barena + OFF_B2N + l * D);
    }
    head_kernel<<<out_size, 256, 0, stream>>>(flag, h, barena, nePtr, naPtr, d_out);
}

// Round 7
// 1366.491 us; speedup vs baseline: 1.2533x; 1.0114x over previous
//
#include <hip/hip_runtime.h>
#include <cstdint>

typedef unsigned short u16;
typedef __bf16  bf16x8 __attribute__((ext_vector_type(8)));
typedef float   f32x4  __attribute__((ext_vector_type(4)));
typedef unsigned short u16x4 __attribute__((ext_vector_type(4)));
typedef unsigned short u16x8 __attribute__((ext_vector_type(8)));

#define S_LEN 3072
#define DMODEL 1024

__device__ __forceinline__ float bf2f(u16 u){ return __uint_as_float(((unsigned)u) << 16); }
__device__ __forceinline__ u16 f2bf(float f){
    unsigned u = __float_as_uint(f);
    return (u16)((u + 0x7fffu + ((u >> 16) & 1u)) >> 16);
}
// mode-aware element fetch -> bf16 bits (mode 0: bf16 input; mode 1: fp32 input)
__device__ __forceinline__ u16 cvld(const void* p, long i, int mode){
    return mode ? f2bf(((const float*)p)[i]) : ((const u16*)p)[i];
}

__device__ __forceinline__ void async16(const void* g, void* l){
    __builtin_amdgcn_global_load_lds(
        (const __attribute__((address_space(1))) unsigned int*)g,
        (__attribute__((address_space(3))) unsigned int*)l, 16, 0, 0);
}

// ---------------------------------------------------------------------------
// dtype sniffer (proven): flag[0]=1 if inputs are fp32, 0 if bf16; flag[1]=0.
// ---------------------------------------------------------------------------
__global__ void sniff_kernel(const u16* __restrict__ x, int* __restrict__ flag)
{
    __shared__ int r[256];
    int tid = threadIdx.x, w = 0;
    for (int j = tid; j < 4096; j += 256){
        int e = (x[j] >> 7) & 0xFF;
        if (e < 90 || e > 140) w++;
    }
    r[tid] = w; __syncthreads();
    for (int s = 128; s > 0; s >>= 1){ if (tid < s) r[tid] += r[tid + s]; __syncthreads(); }
    if (tid == 0){ flag[0] = (r[0] > 256) ? 1 : 0; flag[1] = 0; }
}

// ---------------------------------------------------------------------------
// Scores GEMM 128x128 with fused exp + row-sum epilogue, LDS-repacked stores.
// ---------------------------------------------------------------------------
__global__ __launch_bounds__(256)
void gemm_scores(const u16* __restrict__ A, int lda,
                 const u16* __restrict__ B, int ldb,
                 u16* __restrict__ C, int ldc,
                 float* __restrict__ rowSums,
                 int K, long aBS, long bBS, long cBS)
{
    __shared__ __align__(16) u16 smem[2 * 128 * 64];   // staging, then repack scratch
    u16* Abuf = smem;
    u16* Bbuf = smem + 128 * 64;
    const int tid  = threadIdx.x;
    const int lane = tid & 63, wid = tid >> 6;
    const int wm = wid >> 1, wn = wid & 1;
    const int quad = lane >> 4, lr = lane & 15;
    const int bat = blockIdx.z;

    A += (long)bat * aBS + (long)blockIdx.x * 128 * lda;
    B += (long)bat * bBS + (long)blockIdx.y * 128 * ldb;

    f32x4 zero = {0.f, 0.f, 0.f, 0.f};
    f32x4 acc[4][4];
#pragma unroll
    for (int i = 0; i < 4; i++)
#pragma unroll
        for (int j = 0; j < 4; j++) acc[i][j] = zero;

    int um[4], ukq[4];
#pragma unroll
    for (int i = 0; i < 4; i++){
        int u = i * 256 + tid;
        um[i]  = u >> 3;
        ukq[i] = u & 7;
    }

    const int kTiles = K >> 6;
    for (int kt = 0; kt < kTiles; ++kt){
        const int k0 = kt << 6;
        __syncthreads();
#pragma unroll
        for (int i = 0; i < 4; i++)
            async16(A + (long)um[i] * lda + k0 + ukq[i] * 8, Abuf + (i * 256 + tid) * 8);
#pragma unroll
        for (int i = 0; i < 4; i++)
            async16(B + (long)um[i] * ldb + k0 + ukq[i] * 8, Bbuf + (i * 256 + tid) * 8);
        __syncthreads();
#pragma unroll
        for (int ks = 0; ks < 2; ++ks){
            bf16x8 af[4], bfg[4];
#pragma unroll
            for (int t = 0; t < 4; t++){
                int m  = wm * 64 + t * 16 + lr;
                af[t]  = *(const bf16x8*)(Abuf + (m * 8 + ks * 4 + quad) * 8);
                int n  = wn * 64 + t * 16 + lr;
                bfg[t] = *(const bf16x8*)(Bbuf + (n * 8 + ks * 4 + quad) * 8);
            }
#pragma unroll
            for (int mt = 0; mt < 4; mt++)
#pragma unroll
                for (int nt = 0; nt < 4; nt++)
                    acc[mt][nt] = __builtin_amdgcn_mfma_f32_16x16x32_bf16(
                        af[mt], bfg[nt], acc[mt][nt], 0, 0, 0);
        }
    }

    // ---- epilogue: per-mt LDS repack -> exp -> rowsum -> coalesced store ----
    const int rowBase = blockIdx.x * 128 + wm * 64;
    const int colBase = blockIdx.y * 128 + wn * 64;
    const float scale = 0.0625f;                 // 1/sqrt(256)
    float* scw = (float*)smem + (size_t)wid * (16 * 68);   // 4 x 4352 B = 17.4 KB
    const int row_l = lane >> 2, cq = lane & 3;

#pragma unroll
    for (int mt = 0; mt < 4; ++mt){
        __syncthreads();
#pragma unroll
        for (int nt = 0; nt < 4; nt++)
#pragma unroll
            for (int r = 0; r < 4; r++)
                scw[(quad * 4 + r) * 68 + nt * 16 + lr] = acc[mt][nt][r];
        __syncthreads();
        float vals[16];
#pragma unroll
        for (int j = 0; j < 4; j++)
            *(f32x4*)(vals + j * 4) = *(const f32x4*)(scw + row_l * 68 + cq * 16 + j * 4);
        float rs = 0.f;
        u16x8 pk0, pk1;
#pragma unroll
        for (int i = 0; i < 16; i++){
            float e = __expf(vals[i] * scale);   // |arg|<~2: max-free safe
            rs += e;
            if (i < 8) pk0[i] = f2bf(e); else pk1[i - 8] = f2bf(e);
        }
        rs += __shfl_xor(rs, 1, 64);
        rs += __shfl_xor(rs, 2, 64);
        int row_g = rowBase + mt * 16 + row_l;
        if (cq == 0) atomicAdd(&rowSums[(long)bat * S_LEN + row_g], rs);
        u16* cp = C + (long)bat * cBS + (long)row_g * ldc + colBase + cq * 16;
        *(u16x8*)cp       = pk0;
        *(u16x8*)(cp + 8) = pk1;
    }
}

// ---------------------------------------------------------------------------
// NT GEMM 64x128 tile, LDS-repacked epilogues.
// SPLIT>1: fp32 partials (full-line stores). SPLIT==1 modes:
//   MODE 0: bf16 (+bias), MODE 1: QKV scatter (Q,K natural; V transposed),
//   MODE 2: bias+ReLU bf16.
// ---------------------------------------------------------------------------
template<int SPLIT, int MODE>
__global__ __launch_bounds__(256)
void gemm64(const u16* __restrict__ A, int lda,
            const u16* __restrict__ B, int ldb,
            void* __restrict__ Cv, int ldc,
            const u16* __restrict__ bias,
            int K, long aBS, long bBS, long cBS, long pStride)
{
    __shared__ __align__(16) u16 smem[64 * 64 + 128 * 64];   // 24.5 KB
    u16* Abuf = smem;
    u16* Bbuf = smem + 64 * 64;
    const int tid  = threadIdx.x;
    const int lane = tid & 63, wid = tid >> 6;
    const int quad = lane >> 4, lr = lane & 15;

    const int z   = blockIdx.z;
    const int bat = z / SPLIT;
    const int sp  = z % SPLIT;
    const int kLen = K / SPLIT;

    A += (long)bat * aBS + (long)blockIdx.x * 64 * lda + (long)sp * kLen;
    B += (long)bat * bBS + (long)blockIdx.y * 128 * ldb + (long)sp * kLen;

    f32x4 zero = {0.f, 0.f, 0.f, 0.f};
    f32x4 acc[4][2];
#pragma unroll
    for (int i = 0; i < 4; i++){ acc[i][0] = zero; acc[i][1] = zero; }

    const int kTiles = kLen >> 6;
    for (int kt = 0; kt < kTiles; ++kt){
        const int k0 = kt << 6;
        __syncthreads();
#pragma unroll
        for (int i = 0; i < 2; i++){
            int u = i * 256 + tid;
            async16(A + (long)(u >> 3) * lda + k0 + (u & 7) * 8, Abuf + u * 8);
        }
#pragma unroll
        for (int i = 0; i < 4; i++){
            int u = i * 256 + tid;
            async16(B + (long)(u >> 3) * ldb + k0 + (u & 7) * 8, Bbuf + u * 8);
        }
        __syncthreads();
#pragma unroll
        for (int ks = 0; ks < 2; ++ks){
            bf16x8 af[4], bfg[2];
#pragma unroll
            for (int t = 0; t < 4; t++){
                int m  = t * 16 + lr;
                af[t]  = *(const bf16x8*)(Abuf + (m * 8 + ks * 4 + quad) * 8);
            }
#pragma unroll
            for (int t = 0; t < 2; t++){
                int n  = wid * 32 + t * 16 + lr;
                bfg[t] = *(const bf16x8*)(Bbuf + (n * 8 + ks * 4 + quad) * 8);
            }
#pragma unroll
            for (int mt = 0; mt < 4; mt++)
#pragma unroll
                for (int nt = 0; nt < 2; nt++)
                    acc[mt][nt] = __builtin_amdgcn_mfma_f32_16x16x32_bf16(
                        af[mt], bfg[nt], acc[mt][nt], 0, 0, 0);
        }
    }

    const int rowBase = blockIdx.x * 64;
    const int colBase = blockIdx.y * 128 + wid * 32;
    const int slabw = colBase >> 10;           // block/wave-uniform (128 | 1024)

    if (MODE == 1 && slabw == 2){
        // ---- V^T path: bias, transpose in LDS (u16, stride 72), store along s ----
        u16* scw = smem + (size_t)wid * (32 * 72);           // 4 x 4608 B = 18.4 KB
        __syncthreads();
#pragma unroll
        for (int nt = 0; nt < 2; nt++){
            float bv2 = bf2f(bias[colBase + nt * 16 + lr]);
#pragma unroll
            for (int mt = 0; mt < 4; mt++){
                u16x4 pk;
#pragma unroll
                for (int r = 0; r < 4; r++) pk[r] = f2bf(acc[mt][nt][r] + bv2);
                *(u16x4*)(scw + (nt * 16 + lr) * 72 + mt * 16 + quad * 4) = pk;
            }
        }
        __syncthreads();
        const int e_l = lane >> 1, sh = lane & 1;
        const int e_g = (colBase & 1023) + e_l;
        u16* dst = (u16*)Cv + (long)2 * S_LEN * DMODEL + (long)e_g * S_LEN
                 + rowBase + sh * 32;
#pragma unroll
        for (int j = 0; j < 4; j++)
            *(u16x8*)(dst + j * 8) = *(const u16x8*)(scw + e_l * 72 + sh * 32 + j * 8);
        return;
    }

    // ---- generic path: per-mt fp32 repack (stride 36), coalesced stores ----
    float* scw = (float*)smem + (size_t)wid * (16 * 36);     // 4 x 2304 B = 9.2 KB
    const int row_l = lane >> 2, cq = lane & 3;
#pragma unroll
    for (int mt = 0; mt < 4; ++mt){
        __syncthreads();
#pragma unroll
        for (int nt = 0; nt < 2; nt++)
#pragma unroll
            for (int r = 0; r < 4; r++)
                scw[(quad * 4 + r) * 36 + nt * 16 + lr] = acc[mt][nt][r];
        __syncthreads();
        f32x4 a = *(const f32x4*)(scw + row_l * 36 + cq * 8);
        f32x4 b = *(const f32x4*)(scw + row_l * 36 + cq * 8 + 4);
        const int row_g = rowBase + mt * 16 + row_l;
        const int colg  = colBase + cq * 8;
        if (SPLIT > 1){
            float* P = (float*)Cv + (long)sp * pStride + (long)bat * cBS;
            *(f32x4*)(P + (long)row_g * ldc + colg)     = a;
            *(f32x4*)(P + (long)row_g * ldc + colg + 4) = b;
        } else {
            float bv[8];
            if (bias){
                u16x8 bb = *(const u16x8*)(bias + colg);
#pragma unroll
                for (int i = 0; i < 8; i++) bv[i] = bf2f(bb[i]);
            } else {
#pragma unroll
                for (int i = 0; i < 8; i++) bv[i] = 0.f;
            }
            u16x8 pk;
#pragma unroll
            for (int i = 0; i < 8; i++){
                float v = (i < 4 ? a[i] : b[i - 4]) + bv[i];
                if (MODE == 2) v = fmaxf(v, 0.f);
                pk[i] = f2bf(v);
            }
            long idx;
            if (MODE == 1) idx = ((long)slabw * S_LEN + row_g) * DMODEL + (colg & 1023);
            else           idx = (long)bat * cBS + (long)row_g * ldc + colg;
            *(u16x8*)((u16*)Cv + idx) = pk;
        }
    }
}

// ---------------------------------------------------------------------------
// merged per-layer weight prep (transposes + Wq|Wk|Wv copy), one launch.
// ---------------------------------------------------------------------------
__global__ __launch_bounds__(256)
void wprep(const int* __restrict__ flag, int l,
           const void* Wo, const void* Wf1, const void* Wf2, const void* Wh,
           const void* Wq, const void* Wk, const void* Wv,
           u16* __restrict__ WoT, u16* __restrict__ Wf1T,
           u16* __restrict__ Wf2T, u16* __restrict__ WhT,
           u16* __restrict__ Wcat)
{
    const int mode = *flag;
    const int z = blockIdx.x;
    const int tx = threadIdx.x, ty = threadIdx.y;

    if (z >= 6144){
        int t = ty * 32 + tx;
        long base = (long)(z - 6144) * 2048;
#pragma unroll
        for (int j = 0; j < 8; j++){
            long g = base + j * 256 + t;
            int slab = (int)(g >> 20);
            long r = g & 1048575;
            const void* src = (slab == 0) ? Wq : (slab == 1) ? Wk : Wv;
            Wcat[g] = cvld(src, (long)l * 1048576 + r, mode);
        }
        return;
    }

    const void* in; u16* out; long ib; int R, C, rb, cb;
    if (z < 1024){
        in = Wo; out = WoT; ib = (long)l * 1048576; R = 1024; C = 1024;
        cb = z & 31; rb = z >> 5;
    } else if (z < 3072){
        int t = z - 1024;
        in = Wf1; out = Wf1T; ib = (long)l * 2097152; R = 1024; C = 2048;
        cb = t & 63; rb = t >> 6;
    } else if (z < 5120){
        int t = z - 3072;
        in = Wf2; out = Wf2T; ib = (long)l * 2097152; R = 2048; C = 1024;
        cb = t & 31; rb = t >> 5;
    } else {
        int t = z - 5120;
        int a = t >> 8, u = t & 255;
        in = Wh; out = WhT + (long)a * 262144;
        ib = (long)l * 1048576 + (long)a * 262144; R = 1024; C = 256;
        cb = u & 7; rb = u >> 3;
    }

    __shared__ u16 tbuf[32][34];
    int r0 = rb * 32, c0 = cb * 32;
#pragma unroll
    for (int j = 0; j < 4; j++){
        int r = r0 + ty + j * 8;
        tbuf[ty + j * 8][tx] = cvld(in, ib + (long)r * C + c0 + tx, mode);
    }
    __syncthreads();
#pragma unroll
    for (int j = 0; j < 4; j++){
        int c = c0 + ty + j * 8;
        out[(long)c * R + r0 + tx] = tbuf[tx][ty + j * 8];
    }
}

__global__ __launch_bounds__(256)
void init_h(const int* __restrict__ flag, const void* __restrict__ hin,
            float* __restrict__ h, u16* __restrict__ hbf)
{
    const int mode = *flag;
    long i = (long)blockIdx.x * 256 + threadIdx.x;
    u16 u = cvld(hin, i, mode);
    h[i]   = bf2f(u);
    hbf[i] = u;
}

__global__ __launch_bounds__(256)
void zero_sums(float* __restrict__ p)
{
    p[blockIdx.x * 256 + threadIdx.x] = 0.f;
}

// bias arena layout (elements)
#define OFF_BQKV 0
#define OFF_BH   12288
#define OFF_BO   16384
#define OFF_BF1  20480
#define OFF_BF2  28672
#define OFF_G1   32768
#define OFF_B1N  36864
#define OFF_G2   40960
#define OFF_B2N  45056
#define OFF_WHD  49152
#define OFF_BHD  53248
#define BIAS_TOT 53252

__global__ __launch_bounds__(256)
void cvt_biases(const int* __restrict__ flag,
                const void* bq, const void* bk, const void* bv, const void* bh,
                const void* bo, const void* bf1, const void* bf2,
                const void* g1, const void* b1n, const void* g2, const void* b2n,
                const void* whd, const void* bhd, u16* __restrict__ A)
{
    int i = blockIdx.x * 256 + threadIdx.x;
    if (i >= BIAS_TOT) return;
    const int mode = *flag;
    u16 v;
    if (i < OFF_BH){
        int l = i / 3072, r = i % 3072;
        const void* p = (r < 1024) ? bq : (r < 2048) ? bk : bv;
        v = cvld(p, (long)l * 1024 + (r & 1023), mode);
    }
    else if (i < OFF_BO)  v = cvld(bh,  i - OFF_BH, mode);
    else if (i < OFF_BF1) v = cvld(bo,  i - OFF_BO, mode);
    else if (i < OFF_BF2) v = cvld(bf1, i - OFF_BF1, mode);
    else if (i < OFF_G1)  v = cvld(bf2, i - OFF_BF2, mode);
    else if (i < OFF_B1N) v = cvld(g1,  i - OFF_G1, mode);
    else if (i < OFF_G2)  v = cvld(b1n, i - OFF_B1N, mode);
    else if (i < OFF_B2N) v = cvld(g2,  i - OFF_G2, mode);
    else if (i < OFF_WHD) v = cvld(b2n, i - OFF_B2N, mode);
    else if (i < OFF_BHD) v = cvld(whd, i - OFF_WHD, mode);
    else                  v = cvld(bhd, i - OFF_BHD, mode);
    A[i] = v;
}

// combined QKV+head bias: bqkvh[z*1024+n] = sum_d b_z[d]*WhT[n,d] + bh[l,n]
__global__ __launch_bounds__(256)
void bias_combine(const u16* __restrict__ arena, const u16* __restrict__ WhT,
                  int l, u16* __restrict__ bqkvh)
{
    int i = blockIdx.x * 256 + threadIdx.x;   // < 3072
    int z = i >> 10, n = i & 1023;
    const u16* bz = arena + OFF_BQKV + l * 3072 + z * 1024;
    const u16* wr = WhT + (long)n * 1024;
    float s = bf2f(arena[OFF_BH + l * 1024 + n]);
    for (int d = 0; d < 1024; d += 8){
        bf16x8 w = *(const bf16x8*)(wr + d);
        bf16x8 b = *(const bf16x8*)(bz + d);
#pragma unroll
        for (int j = 0; j < 8; j++) s += (float)w[j] * (float)b[j];
    }
    bqkvh[i] = f2bf(s);
}

__device__ __forceinline__ float blockSum(float v, float* red){
    int lane = threadIdx.x & 63, wid = threadIdx.x >> 6;
#pragma unroll
    for (int o = 32; o > 0; o >>= 1) v += __shfl_down(v, o, 64);
    __syncthreads();
    if (lane == 0) red[wid] = v;
    __syncthreads();
    return red[0] + red[1] + red[2] + red[3];
}

// h = LN(h + bias + sum_{sp<nparts} parts[sp]) * g + b
__global__ __launch_bounds__(256)
void ln_fused(float* __restrict__ h, const float* __restrict__ parts, long pStride,
              int nparts, const u16* __restrict__ bias, u16* __restrict__ hbf,
              const u16* __restrict__ g, const u16* __restrict__ b)
{
    __shared__ float red[4];
    long base = (long)blockIdx.x * DMODEL;
    int tid = threadIdx.x;
    float v[4];
    float s = 0.f;
#pragma unroll
    for (int j = 0; j < 4; j++){
        int c = tid + j * 256;
        float x = bf2f(bias[c]);
        for (int sp = 0; sp < nparts; sp++) x += parts[(long)sp * pStride + base + c];
        float r = h[base + c] + x;
        v[j] = r; s += r;
    }
    float mu = blockSum(s, red) * (1.f / DMODEL);
    float s2 = 0.f;
#pragma unroll
    for (int j = 0; j < 4; j++){ float d = v[j] - mu; s2 += d * d; }
    float var = blockSum(s2, red) * (1.f / DMODEL);
    float inv = rsqrtf(var + 1e-5f);
#pragma unroll
    for (int j = 0; j < 4; j++){
        int c = tid + j * 256;
        float y = (v[j] - mu) * inv * bf2f(g[c]) + bf2f(b[c]);
        h[base + c]   = y;
        hbf[base + c] = f2bf(y);
    }
}

// ctx merge: out = (sum_sp parts[sp]) / rowSums[head][row]  -> bf16
__global__ __launch_bounds__(256)
void reduce_div(const float* __restrict__ parts, long pStride, int nsplit,
                const float* __restrict__ l, u16* __restrict__ out)
{
    long i0 = ((long)blockIdx.x * 256 + threadIdx.x) * 4;
    int row  = (int)(i0 >> 10);
    int head = (int)((i0 & 1023) >> 8);
    float inv = 1.f / l[(long)head * S_LEN + row];
#pragma unroll
    for (int j = 0; j < 4; j++){
        long i = i0 + j;
        float s = 0.f;
        for (int sp = 0; sp < nsplit; sp++) s += parts[(long)sp * pStride + i];
        out[i] = f2bf(s * inv);
    }
}

__global__ __launch_bounds__(256)
void head_kernel(const int* __restrict__ flag, const float* __restrict__ h,
                 const u16* __restrict__ arena, const int* __restrict__ nePtr,
                 const int* __restrict__ naPtr, void* __restrict__ outp)
{
    __shared__ float red[4];
    int o = blockIdx.x;
    int ne = *nePtr, na = *naPtr;
    int widx, row;
    if (o < 3 * na){ widx = o / na; row = ne + o % na; }
    else           { widx = 3;      row = o - 3 * na; }
    int tid = threadIdx.x;
    const float* hr = h + (long)row * DMODEL;
    const u16*   w  = arena + OFF_WHD + widx * DMODEL;
    float s = 0.f;
#pragma unroll
    for (int j = 0; j < 4; j++){ int c = tid + j * 256; s += hr[c] * bf2f(w[c]); }
    s = blockSum(s, red);
    if (tid == 0){
        float r = s + bf2f(arena[OFF_BHD + widx]);
        if (*flag) ((float*)outp)[o] = r;
        else       ((u16*)outp)[o]   = f2bf(r);
    }
}

// ---------------------------------------------------------------------------
extern "C" void kernel_launch(void* const* d_in, const int* in_sizes, int n_in,
                              void* d_out, int out_size, void* d_ws, size_t ws_size,
                              hipStream_t stream)
{
    const void* hidden = d_in[0];
    const void* Wq  = d_in[1];  const void* bq  = d_in[2];
    const void* Wk  = d_in[3];  const void* bk  = d_in[4];
    const void* Wv  = d_in[5];  const void* bv  = d_in[6];
    const void* Wh  = d_in[7];  const void* bh  = d_in[8];
    const void* Wo  = d_in[9];  const void* bo  = d_in[10];
    const void* g1  = d_in[11]; const void* b1n = d_in[12];
    const void* g2  = d_in[13]; const void* b2n = d_in[14];
    const void* Wf1 = d_in[15]; const void* bf1 = d_in[16];
    const void* Wf2 = d_in[17]; const void* bf2 = d_in[18];
    const void* Whd = d_in[19]; const void* bhd = d_in[20];
    const int* nePtr = (const int*)d_in[21];
    const int* naPtr = (const int*)d_in[22];

    const long D = 1024, S = 3072, L = 4, DK = 256;

    char* ws = (char*)d_ws;
    size_t off = 0;
    auto alloc = [&](size_t bytes)->char*{
        char* p = ws + off;
        off = (off + bytes + 255) & ~(size_t)255;
        return p;
    };
    int*  flag   = (int*)alloc(256);
    u16*  barena = (u16*)alloc(BIAS_TOT * 2);
    u16*  bqkvh  = (u16*)alloc(3 * D * 2);
    float* rowSums = (float*)alloc(4 * S * 4);
    u16*  WhT    = (u16*)alloc(D * D * 2);
    u16*  WqkvhT = (u16*)alloc(3 * D * D * 2);     // combined (Wz@Wh)^T (3072x1024)
    u16*  WoT    = (u16*)alloc(D * D * 2);
    u16*  Wf1T   = (u16*)alloc(2 * D * D * 2);
    u16*  Wf2T   = (u16*)alloc(2 * D * D * 2);
    float* h     = (float*)alloc(S * D * 4);
    u16*  hbf    = (u16*)alloc(S * D * 2);
    u16*  qkvh   = (u16*)alloc(3 * S * D * 2);     // [Qh;Kh;V^T] (slab 2 = V^T e x s)
    u16*  ctx    = (u16*)alloc(S * D * 2);
    size_t baseEnd = off;

    size_t reg4 = (size_t)4 * S * S * 2;                       // 75.5 MB
    size_t reg1 = (size_t)S * S * 2 + (size_t)S * 2 * D * 2;   // 1-head scores + ffn1
    int HBv = (ws_size >= baseEnd + reg4 + 2 * (size_t)S * D * 4 + 4096) ? 4 : 1;
    char* regionB = alloc(HBv == 4 ? reg4 : reg1);
    size_t endB = off;
    size_t cp1 = (size_t)S * D * 4;
    int ctxSplit = (ws_size >= endB + 2 * cp1 + 4096) ? 2 : 1;
    float* ctxParts = (float*)alloc((size_t)ctxSplit * cp1);

    u16* scoresP = (u16*)regionB;
    u16* Wcat    = (u16*)regionB;                  // prep phase (scores dead)
    float* woParts = (float*)regionB;              // 2 x (S*D) fp32 (scores dead)
    u16* ffn1;                                     // (S x 2048) bf16
    float* f2Parts;                                // 2 x (S*D) fp32
    if (HBv == 4){
        ffn1    = (u16*)regionB;
        f2Parts = (float*)(regionB + (size_t)S * 2 * D * 2);
    } else {
        ffn1    = (u16*)(regionB + (size_t)S * S * 2);
        f2Parts = (float*)ctxParts;                // ctx partials dead by FFN2
    }

    const long pSD = S * D;

    dim3 tb(32, 8);
    sniff_kernel<<<1, 256, 0, stream>>>((const u16*)hidden, flag);
    cvt_biases<<<(BIAS_TOT + 255) / 256, 256, 0, stream>>>(
        flag, bq, bk, bv, bh, bo, bf1, bf2, g1, b1n, g2, b2n, Whd, bhd, barena);
    init_h<<<(int)(S * D / 256), 256, 0, stream>>>(flag, hidden, h, hbf);

    for (int l = 0; l < L; ++l){
        // ---- weight prep ----
        wprep<<<7680, tb, 0, stream>>>(flag, l, Wo, Wf1, Wf2, Wh, Wq, Wk, Wv,
                                       WoT, Wf1T, Wf2T, WhT, Wcat);
        gemm64<1, 0><<<dim3(16, 8, 3), 256, 0, stream>>>(
            WhT, 1024, Wcat, 1024, WqkvhT, 1024, nullptr,
            1024, 0, (long)D * D, (long)D * D, 0);
        bias_combine<<<12, 256, 0, stream>>>(barena, WhT, l, bqkvh);

        // ---- fused QKV+head projection; V written transposed into slab 2 ----
        gemm64<1, 1><<<dim3(48, 24, 1), 256, 0, stream>>>(
            hbf, 1024, WqkvhT, 1024, qkvh, 0, bqkvh,
            1024, 0, 0, 0, 0);

        // ---- attention: scores+exp+rowsums, then ctx (split-K) ----
        zero_sums<<<48, 256, 0, stream>>>(rowSums);
        if (HBv == 4){
            gemm_scores<<<dim3(24, 24, 4), 256, 0, stream>>>(
                qkvh, 1024, qkvh + S * D, 1024, scoresP, (int)S,
                rowSums, (int)DK, DK, DK, (long)S * S);
            gemm64<2, 0><<<dim3(48, 2, 8), 256, 0, stream>>>(
                scoresP, (int)S, qkvh + 2 * S * D, (int)S,
                ctxParts, 1024, nullptr, (int)S,
                (long)S * S, (long)DK * S, DK, pSD);
        } else {
            for (int h0 = 0; h0 < 4; ++h0){
                gemm_scores<<<dim3(24, 24, 1), 256, 0, stream>>>(
                    qkvh + h0 * DK, 1024, qkvh + S * D + h0 * DK, 1024,
                    scoresP, (int)S, rowSums + h0 * S, (int)DK, 0, 0, 0);
                gemm64<2, 0><<<dim3(48, 2, 2), 256, 0, stream>>>(
                    scoresP, (int)S, qkvh + 2 * S * D + (long)h0 * DK * S, (int)S,
                    ctxParts + h0 * DK, 1024, nullptr, (int)S,
                    0, 0, 0, ctxSplit == 2 ? pSD : 0);
            }
        }
        reduce_div<<<3072, 256, 0, stream>>>(ctxParts, pSD, ctxSplit, rowSums, ctx);

        // ---- attn_out: gemm64 split-2; reduce fused into LN ----
        gemm64<2, 0><<<dim3(48, 8, 2), 256, 0, stream>>>(
            ctx, 1024, WoT, 1024, woParts, 1024, nullptr,
            1024, 0, 0, 0, pSD);
        ln_fused<<<3072, 256, 0, stream>>>(h, woParts, pSD, 2, barena + OFF_BO + l * D,
                                           hbf, barena + OFF_G1 + l * D, barena + OFF_B1N + l * D);
        // ---- FFN1: single gemm64, bias+ReLU fused ----
        gemm64<1, 2><<<dim3(48, 16, 1), 256, 0, stream>>>(
            hbf, 1024, Wf1T, 1024, ffn1, 2048, barena + OFF_BF1 + l * 2 * D,
            1024, 0, 0, 0, 0);
        // ---- FFN2: gemm64 split-2; reduce fused into LN ----
        gemm64<2, 0><<<dim3(48, 8, 2), 256, 0, stream>>>(
            ffn1, 2048, Wf2T, 2048, f2Parts, 1024, nullptr,
            2048, 0, 0, 0, pSD);
        ln_fused<<<3072, 256, 0, stream>>>(h, f2Parts, pSD, 2, barena + OFF_BF2 + l * D,
                                           hbf, barena + OFF_G2 + l * D, barena + OFF_B2N + l * D);
    }
    head_kernel<<<out_size, 256, 0, stream>>>(flag, h, barena, nePtr, naPtr, d_out);
}

// Round 8
// 1363.347 us; speedup vs baseline: 1.2562x; 1.0023x over previous
//
#include <hip/hip_runtime.h>
#include <cstdint>

typedef unsigned short u16;
typedef __bf16  bf16x8 __attribute__((ext_vector_type(8)));
typedef float   f32x4  __attribute__((ext_vector_type(4)));
typedef unsigned short u16x4 __attribute__((ext_vector_type(4)));
typedef unsigned short u16x8 __attribute__((ext_vector_type(8)));

#define S_LEN 3072
#define DMODEL 1024

__device__ __forceinline__ float bf2f(u16 u){ return __uint_as_float(((unsigned)u) << 16); }
__device__ __forceinline__ u16 f2bf(float f){
    unsigned u = __float_as_uint(f);
    return (u16)((u + 0x7fffu + ((u >> 16) & 1u)) >> 16);
}
// mode-aware element fetch -> bf16 bits (mode 0: bf16 input; mode 1: fp32 input)
__device__ __forceinline__ u16 cvld(const void* p, long i, int mode){
    return mode ? f2bf(((const float*)p)[i]) : ((const u16*)p)[i];
}

__device__ __forceinline__ void async16(const void* g, void* l){
    __builtin_amdgcn_global_load_lds(
        (const __attribute__((address_space(1))) unsigned int*)g,
        (__attribute__((address_space(3))) unsigned int*)l, 16, 0, 0);
}

// ---------------------------------------------------------------------------
// dtype sniffer (proven): flag[0]=1 if inputs are fp32, 0 if bf16; flag[1]=0.
// ---------------------------------------------------------------------------
__global__ void sniff_kernel(const u16* __restrict__ x, int* __restrict__ flag)
{
    __shared__ int r[256];
    int tid = threadIdx.x, w = 0;
    for (int j = tid; j < 4096; j += 256){
        int e = (x[j] >> 7) & 0xFF;
        if (e < 90 || e > 140) w++;
    }
    r[tid] = w; __syncthreads();
    for (int s = 128; s > 0; s >>= 1){ if (tid < s) r[tid] += r[tid + s]; __syncthreads(); }
    if (tid == 0){ flag[0] = (r[0] > 256) ? 1 : 0; flag[1] = 0; }
}

// ---------------------------------------------------------------------------
// Scores GEMM 128x128 with fused exp + row-sum epilogue, LDS-repacked stores.
// Single barrier after K-loop; repack scratch is wave-private.
// ---------------------------------------------------------------------------
__global__ __launch_bounds__(256)
void gemm_scores(const u16* __restrict__ A, int lda,
                 const u16* __restrict__ B, int ldb,
                 u16* __restrict__ C, int ldc,
                 float* __restrict__ rowSums,
                 int K, long aBS, long bBS, long cBS)
{
    __shared__ __align__(16) u16 smem[2 * 128 * 64];
    u16* Abuf = smem;
    u16* Bbuf = smem + 128 * 64;
    const int tid  = threadIdx.x;
    const int lane = tid & 63, wid = tid >> 6;
    const int wm = wid >> 1, wn = wid & 1;
    const int quad = lane >> 4, lr = lane & 15;
    const int bat = blockIdx.z;

    A += (long)bat * aBS + (long)blockIdx.x * 128 * lda;
    B += (long)bat * bBS + (long)blockIdx.y * 128 * ldb;

    f32x4 zero = {0.f, 0.f, 0.f, 0.f};
    f32x4 acc[4][4];
#pragma unroll
    for (int i = 0; i < 4; i++)
#pragma unroll
        for (int j = 0; j < 4; j++) acc[i][j] = zero;

    int um[4], ukq[4];
#pragma unroll
    for (int i = 0; i < 4; i++){
        int u = i * 256 + tid;
        um[i]  = u >> 3;
        ukq[i] = u & 7;
    }

    const int kTiles = K >> 6;
    for (int kt = 0; kt < kTiles; ++kt){
        const int k0 = kt << 6;
        __syncthreads();
#pragma unroll
        for (int i = 0; i < 4; i++)
            async16(A + (long)um[i] * lda + k0 + ukq[i] * 8, Abuf + (i * 256 + tid) * 8);
#pragma unroll
        for (int i = 0; i < 4; i++)
            async16(B + (long)um[i] * ldb + k0 + ukq[i] * 8, Bbuf + (i * 256 + tid) * 8);
        __syncthreads();
#pragma unroll
        for (int ks = 0; ks < 2; ++ks){
            bf16x8 af[4], bfg[4];
#pragma unroll
            for (int t = 0; t < 4; t++){
                int m  = wm * 64 + t * 16 + lr;
                af[t]  = *(const bf16x8*)(Abuf + (m * 8 + ks * 4 + quad) * 8);
                int n  = wn * 64 + t * 16 + lr;
                bfg[t] = *(const bf16x8*)(Bbuf + (n * 8 + ks * 4 + quad) * 8);
            }
#pragma unroll
            for (int mt = 0; mt < 4; mt++)
#pragma unroll
                for (int nt = 0; nt < 4; nt++)
                    acc[mt][nt] = __builtin_amdgcn_mfma_f32_16x16x32_bf16(
                        af[mt], bfg[nt], acc[mt][nt], 0, 0, 0);
        }
    }

    // ---- epilogue: wave-private LDS repack -> exp -> rowsum -> wide store ----
    const int rowBase = blockIdx.x * 128 + wm * 64;
    const int colBase = blockIdx.y * 128 + wn * 64;
    const float scale = 0.0625f;                 // 1/sqrt(256)
    float* scw = (float*)smem + (size_t)wid * (16 * 68);   // 4 x 4352 B
    const int row_l = lane >> 2, cq = lane & 3;

    __syncthreads();   // all waves done reading Abuf/Bbuf
#pragma unroll
    for (int mt = 0; mt < 4; ++mt){
#pragma unroll
        for (int nt = 0; nt < 4; nt++)
#pragma unroll
            for (int r = 0; r < 4; r++)
                scw[(quad * 4 + r) * 68 + nt * 16 + lr] = acc[mt][nt][r];
        float vals[16];
#pragma unroll
        for (int j = 0; j < 4; j++)
            *(f32x4*)(vals + j * 4) = *(const f32x4*)(scw + row_l * 68 + cq * 16 + j * 4);
        float rs = 0.f;
        u16x8 pk0, pk1;
#pragma unroll
        for (int i = 0; i < 16; i++){
            float e = __expf(vals[i] * scale);   // |arg|<~2: max-free safe
            rs += e;
            if (i < 8) pk0[i] = f2bf(e); else pk1[i - 8] = f2bf(e);
        }
        rs += __shfl_xor(rs, 1, 64);
        rs += __shfl_xor(rs, 2, 64);
        int row_g = rowBase + mt * 16 + row_l;
        if (cq == 0) atomicAdd(&rowSums[(long)bat * S_LEN + row_g], rs);
        u16* cp = C + (long)bat * cBS + (long)row_g * ldc + colBase + cq * 16;
        *(u16x8*)cp       = pk0;
        *(u16x8*)(cp + 8) = pk1;
    }
}

// ---------------------------------------------------------------------------
// NT GEMM 64x128 tile, LDS-repacked epilogues (single barrier).
// SPLIT>1: bf16 partials at sp*pStride + bat*cBS (pStride in elements).
// SPLIT==1 modes: 0 bf16(+bias), 1 QKV scatter (Q,K natural; V transposed),
//                 2 bias+ReLU, 3 bf16 scaled by 1/rs[row] (ctx).
// ---------------------------------------------------------------------------
template<int SPLIT, int MODE>
__global__ __launch_bounds__(256)
void gemm64(const u16* __restrict__ A, int lda,
            const u16* __restrict__ B, int ldb,
            void* __restrict__ Cv, int ldc,
            const u16* __restrict__ bias,
            int K, long aBS, long bBS, long cBS, long pStride,
            const float* __restrict__ rs)
{
    __shared__ __align__(16) u16 smem[64 * 64 + 128 * 64];   // 24.5 KB
    u16* Abuf = smem;
    u16* Bbuf = smem + 64 * 64;
    const int tid  = threadIdx.x;
    const int lane = tid & 63, wid = tid >> 6;
    const int quad = lane >> 4, lr = lane & 15;

    const int z   = blockIdx.z;
    const int bat = z / SPLIT;
    const int sp  = z % SPLIT;
    const int kLen = K / SPLIT;

    A += (long)bat * aBS + (long)blockIdx.x * 64 * lda + (long)sp * kLen;
    B += (long)bat * bBS + (long)blockIdx.y * 128 * ldb + (long)sp * kLen;

    f32x4 zero = {0.f, 0.f, 0.f, 0.f};
    f32x4 acc[4][2];
#pragma unroll
    for (int i = 0; i < 4; i++){ acc[i][0] = zero; acc[i][1] = zero; }

    const int kTiles = kLen >> 6;
    for (int kt = 0; kt < kTiles; ++kt){
        const int k0 = kt << 6;
        __syncthreads();
#pragma unroll
        for (int i = 0; i < 2; i++){
            int u = i * 256 + tid;
            async16(A + (long)(u >> 3) * lda + k0 + (u & 7) * 8, Abuf + u * 8);
        }
#pragma unroll
        for (int i = 0; i < 4; i++){
            int u = i * 256 + tid;
            async16(B + (long)(u >> 3) * ldb + k0 + (u & 7) * 8, Bbuf + u * 8);
        }
        __syncthreads();
#pragma unroll
        for (int ks = 0; ks < 2; ++ks){
            bf16x8 af[4], bfg[2];
#pragma unroll
            for (int t = 0; t < 4; t++){
                int m  = t * 16 + lr;
                af[t]  = *(const bf16x8*)(Abuf + (m * 8 + ks * 4 + quad) * 8);
            }
#pragma unroll
            for (int t = 0; t < 2; t++){
                int n  = wid * 32 + t * 16 + lr;
                bfg[t] = *(const bf16x8*)(Bbuf + (n * 8 + ks * 4 + quad) * 8);
            }
#pragma unroll
            for (int mt = 0; mt < 4; mt++)
#pragma unroll
                for (int nt = 0; nt < 2; nt++)
                    acc[mt][nt] = __builtin_amdgcn_mfma_f32_16x16x32_bf16(
                        af[mt], bfg[nt], acc[mt][nt], 0, 0, 0);
        }
    }

    const int rowBase = blockIdx.x * 64;
    const int colBase = blockIdx.y * 128 + wid * 32;
    const int slabw = colBase >> 10;           // wave-uniform

    __syncthreads();   // all waves done reading Abuf/Bbuf

    if (MODE == 1 && slabw == 2){
        // ---- V^T path: bias, transpose in LDS (u16, stride 72), store along s ----
        u16* scw = smem + (size_t)wid * (32 * 72);
#pragma unroll
        for (int nt = 0; nt < 2; nt++){
            float bv2 = bf2f(bias[colBase + nt * 16 + lr]);
#pragma unroll
            for (int mt = 0; mt < 4; mt++){
                u16x4 pk;
#pragma unroll
                for (int r = 0; r < 4; r++) pk[r] = f2bf(acc[mt][nt][r] + bv2);
                *(u16x4*)(scw + (nt * 16 + lr) * 72 + mt * 16 + quad * 4) = pk;
            }
        }
        const int e_l = lane >> 1, sh = lane & 1;
        const int e_g = (colBase & 1023) + e_l;
        u16* dst = (u16*)Cv + (long)2 * S_LEN * DMODEL + (long)e_g * S_LEN
                 + rowBase + sh * 32;
#pragma unroll
        for (int j = 0; j < 4; j++)
            *(u16x8*)(dst + j * 8) = *(const u16x8*)(scw + e_l * 72 + sh * 32 + j * 8);
        return;
    }

    // ---- generic path: per-mt wave-private fp32 repack, coalesced stores ----
    float* scw = (float*)smem + (size_t)wid * (16 * 36);
    const int row_l = lane >> 2, cq = lane & 3;
#pragma unroll
    for (int mt = 0; mt < 4; ++mt){
#pragma unroll
        for (int nt = 0; nt < 2; nt++)
#pragma unroll
            for (int r = 0; r < 4; r++)
                scw[(quad * 4 + r) * 36 + nt * 16 + lr] = acc[mt][nt][r];
        f32x4 a = *(const f32x4*)(scw + row_l * 36 + cq * 8);
        f32x4 b = *(const f32x4*)(scw + row_l * 36 + cq * 8 + 4);
        const int row_g = rowBase + mt * 16 + row_l;
        const int colg  = colBase + cq * 8;
        float inv = 1.f;
        if (MODE == 3) inv = 1.f / rs[(long)bat * S_LEN + row_g];
        float bv[8];
        if (SPLIT == 1 && MODE != 3 && bias){
            u16x8 bb = *(const u16x8*)(bias + colg);
#pragma unroll
            for (int i = 0; i < 8; i++) bv[i] = bf2f(bb[i]);
        } else {
#pragma unroll
            for (int i = 0; i < 8; i++) bv[i] = 0.f;
        }
        u16x8 pk;
#pragma unroll
        for (int i = 0; i < 8; i++){
            float v = (i < 4 ? a[i] : b[i - 4]) + bv[i];
            if (MODE == 2) v = fmaxf(v, 0.f);
            if (MODE == 3) v *= inv;
            pk[i] = f2bf(v);
        }
        long idx;
        if (SPLIT > 1)      idx = (long)sp * pStride + (long)bat * cBS + (long)row_g * ldc + colg;
        else if (MODE == 1) idx = ((long)slabw * S_LEN + row_g) * DMODEL + (colg & 1023);
        else                idx = (long)bat * cBS + (long)row_g * ldc + colg;
        *(u16x8*)((u16*)Cv + idx) = pk;
    }
}

// ---------------------------------------------------------------------------
// merged per-layer prep: weight transposes + Wq|Wk|Wv copy + rowSums zero.
// grid.x = 7728, block (32,8).
// ---------------------------------------------------------------------------
__global__ __launch_bounds__(256)
void wprep(const int* __restrict__ flag, int l,
           const void* Wo, const void* Wf1, const void* Wf2, const void* Wh,
           const void* Wq, const void* Wk, const void* Wv,
           u16* __restrict__ WoT, u16* __restrict__ Wf1T,
           u16* __restrict__ Wf2T, u16* __restrict__ WhT,
           u16* __restrict__ Wcat, float* __restrict__ rowSums)
{
    const int mode = *flag;
    const int z = blockIdx.x;
    const int tx = threadIdx.x, ty = threadIdx.y;

    if (z >= 7680){
        int idx = (z - 7680) * 256 + ty * 32 + tx;   // < 12288
        rowSums[idx] = 0.f;
        return;
    }
    if (z >= 6144){
        int t = ty * 32 + tx;
        long base = (long)(z - 6144) * 2048;
#pragma unroll
        for (int j = 0; j < 8; j++){
            long g = base + j * 256 + t;
            int slab = (int)(g >> 20);
            long r = g & 1048575;
            const void* src = (slab == 0) ? Wq : (slab == 1) ? Wk : Wv;
            Wcat[g] = cvld(src, (long)l * 1048576 + r, mode);
        }
        return;
    }

    const void* in; u16* out; long ib; int R, C, rb, cb;
    if (z < 1024){
        in = Wo; out = WoT; ib = (long)l * 1048576; R = 1024; C = 1024;
        cb = z & 31; rb = z >> 5;
    } else if (z < 3072){
        int t = z - 1024;
        in = Wf1; out = Wf1T; ib = (long)l * 2097152; R = 1024; C = 2048;
        cb = t & 63; rb = t >> 6;
    } else if (z < 5120){
        int t = z - 3072;
        in = Wf2; out = Wf2T; ib = (long)l * 2097152; R = 2048; C = 1024;
        cb = t & 31; rb = t >> 5;
    } else {
        int t = z - 5120;
        int a = t >> 8, u = t & 255;
        in = Wh; out = WhT + (long)a * 262144;
        ib = (long)l * 1048576 + (long)a * 262144; R = 1024; C = 256;
        cb = u & 7; rb = u >> 3;
    }

    __shared__ u16 tbuf[32][34];
    int r0 = rb * 32, c0 = cb * 32;
#pragma unroll
    for (int j = 0; j < 4; j++){
        int r = r0 + ty + j * 8;
        tbuf[ty + j * 8][tx] = cvld(in, ib + (long)r * C + c0 + tx, mode);
    }
    __syncthreads();
#pragma unroll
    for (int j = 0; j < 4; j++){
        int c = c0 + ty + j * 8;
        out[(long)c * R + r0 + tx] = tbuf[tx][ty + j * 8];
    }
}

__global__ __launch_bounds__(256)
void init_h(const int* __restrict__ flag, const void* __restrict__ hin,
            float* __restrict__ h, u16* __restrict__ hbf)
{
    const int mode = *flag;
    long i = (long)blockIdx.x * 256 + threadIdx.x;
    u16 u = cvld(hin, i, mode);
    h[i]   = bf2f(u);
    hbf[i] = u;
}

// bias arena layout (elements)
#define OFF_BQKV 0
#define OFF_BH   12288
#define OFF_BO   16384
#define OFF_BF1  20480
#define OFF_BF2  28672
#define OFF_G1   32768
#define OFF_B1N  36864
#define OFF_G2   40960
#define OFF_B2N  45056
#define OFF_WHD  49152
#define OFF_BHD  53248
#define BIAS_TOT 53252

__global__ __launch_bounds__(256)
void cvt_biases(const int* __restrict__ flag,
                const void* bq, const void* bk, const void* bv, const void* bh,
                const void* bo, const void* bf1, const void* bf2,
                const void* g1, const void* b1n, const void* g2, const void* b2n,
                const void* whd, const void* bhd, u16* __restrict__ A)
{
    int i = blockIdx.x * 256 + threadIdx.x;
    if (i >= BIAS_TOT) return;
    const int mode = *flag;
    u16 v;
    if (i < OFF_BH){
        int l = i / 3072, r = i % 3072;
        const void* p = (r < 1024) ? bq : (r < 2048) ? bk : bv;
        v = cvld(p, (long)l * 1024 + (r & 1023), mode);
    }
    else if (i < OFF_BO)  v = cvld(bh,  i - OFF_BH, mode);
    else if (i < OFF_BF1) v = cvld(bo,  i - OFF_BO, mode);
    else if (i < OFF_BF2) v = cvld(bf1, i - OFF_BF1, mode);
    else if (i < OFF_G1)  v = cvld(bf2, i - OFF_BF2, mode);
    else if (i < OFF_B1N) v = cvld(g1,  i - OFF_G1, mode);
    else if (i < OFF_G2)  v = cvld(b1n, i - OFF_B1N, mode);
    else if (i < OFF_B2N) v = cvld(g2,  i - OFF_G2, mode);
    else if (i < OFF_WHD) v = cvld(b2n, i - OFF_B2N, mode);
    else if (i < OFF_BHD) v = cvld(whd, i - OFF_WHD, mode);
    else                  v = cvld(bhd, i - OFF_BHD, mode);
    A[i] = v;
}

// combined QKV+head bias: bqkvh[z*1024+n] = sum_d b_z[d]*WhT[n,d] + bh[l,n]
__global__ __launch_bounds__(256)
void bias_combine(const u16* __restrict__ arena, const u16* __restrict__ WhT,
                  int l, u16* __restrict__ bqkvh)
{
    int i = blockIdx.x * 256 + threadIdx.x;   // < 3072
    int z = i >> 10, n = i & 1023;
    const u16* bz = arena + OFF_BQKV + l * 3072 + z * 1024;
    const u16* wr = WhT + (long)n * 1024;
    float s = bf2f(arena[OFF_BH + l * 1024 + n]);
    for (int d = 0; d < 1024; d += 8){
        bf16x8 w = *(const bf16x8*)(wr + d);
        bf16x8 b = *(const bf16x8*)(bz + d);
#pragma unroll
        for (int j = 0; j < 8; j++) s += (float)w[j] * (float)b[j];
    }
    bqkvh[i] = f2bf(s);
}

__device__ __forceinline__ float blockSum(float v, float* red){
    int lane = threadIdx.x & 63, wid = threadIdx.x >> 6;
#pragma unroll
    for (int o = 32; o > 0; o >>= 1) v += __shfl_down(v, o, 64);
    __syncthreads();
    if (lane == 0) red[wid] = v;
    __syncthreads();
    return red[0] + red[1] + red[2] + red[3];
}

// h = LN(h + bias + sum_{sp<nparts} bf16 parts[sp]) * g + b
__global__ __launch_bounds__(256)
void ln_fused(float* __restrict__ h, const u16* __restrict__ parts, long pStride,
              int nparts, const u16* __restrict__ bias, u16* __restrict__ hbf,
              const u16* __restrict__ g, const u16* __restrict__ b)
{
    __shared__ float red[4];
    long base = (long)blockIdx.x * DMODEL;
    int tid = threadIdx.x;
    float v[4];
    float s = 0.f;
#pragma unroll
    for (int j = 0; j < 4; j++){
        int c = tid + j * 256;
        float x = bf2f(bias[c]);
        for (int sp = 0; sp < nparts; sp++) x += bf2f(parts[(long)sp * pStride + base + c]);
        float r = h[base + c] + x;
        v[j] = r; s += r;
    }
    float mu = blockSum(s, red) * (1.f / DMODEL);
    float s2 = 0.f;
#pragma unroll
    for (int j = 0; j < 4; j++){ float d = v[j] - mu; s2 += d * d; }
    float var = blockSum(s2, red) * (1.f / DMODEL);
    float inv = rsqrtf(var + 1e-5f);
#pragma unroll
    for (int j = 0; j < 4; j++){
        int c = tid + j * 256;
        float y = (v[j] - mu) * inv * bf2f(g[c]) + bf2f(b[c]);
        h[base + c]   = y;
        hbf[base + c] = f2bf(y);
    }
}

__global__ __launch_bounds__(256)
void head_kernel(const int* __restrict__ flag, const float* __restrict__ h,
                 const u16* __restrict__ arena, const int* __restrict__ nePtr,
                 const int* __restrict__ naPtr, void* __restrict__ outp)
{
    __shared__ float red[4];
    int o = blockIdx.x;
    int ne = *nePtr, na = *naPtr;
    int widx, row;
    if (o < 3 * na){ widx = o / na; row = ne + o % na; }
    else           { widx = 3;      row = o - 3 * na; }
    int tid = threadIdx.x;
    const float* hr = h + (long)row * DMODEL;
    const u16*   w  = arena + OFF_WHD + widx * DMODEL;
    float s = 0.f;
#pragma unroll
    for (int j = 0; j < 4; j++){ int c = tid + j * 256; s += hr[c] * bf2f(w[c]); }
    s = blockSum(s, red);
    if (tid == 0){
        float r = s + bf2f(arena[OFF_BHD + widx]);
        if (*flag) ((float*)outp)[o] = r;
        else       ((u16*)outp)[o]   = f2bf(r);
    }
}

// ---------------------------------------------------------------------------
extern "C" void kernel_launch(void* const* d_in, const int* in_sizes, int n_in,
                              void* d_out, int out_size, void* d_ws, size_t ws_size,
                              hipStream_t stream)
{
    const void* hidden = d_in[0];
    const void* Wq  = d_in[1];  const void* bq  = d_in[2];
    const void* Wk  = d_in[3];  const void* bk  = d_in[4];
    const void* Wv  = d_in[5];  const void* bv  = d_in[6];
    const void* Wh  = d_in[7];  const void* bh  = d_in[8];
    const void* Wo  = d_in[9];  const void* bo  = d_in[10];
    const void* g1  = d_in[11]; const void* b1n = d_in[12];
    const void* g2  = d_in[13]; const void* b2n = d_in[14];
    const void* Wf1 = d_in[15]; const void* bf1 = d_in[16];
    const void* Wf2 = d_in[17]; const void* bf2 = d_in[18];
    const void* Whd = d_in[19]; const void* bhd = d_in[20];
    const int* nePtr = (const int*)d_in[21];
    const int* naPtr = (const int*)d_in[22];

    const long D = 1024, S = 3072, L = 4, DK = 256;

    char* ws = (char*)d_ws;
    size_t off = 0;
    auto alloc = [&](size_t bytes)->char*{
        char* p = ws + off;
        off = (off + bytes + 255) & ~(size_t)255;
        return p;
    };
    int*  flag   = (int*)alloc(256);
    u16*  barena = (u16*)alloc(BIAS_TOT * 2);
    u16*  bqkvh  = (u16*)alloc(3 * D * 2);
    float* rowSums = (float*)alloc(4 * S * 4);
    u16*  WhT    = (u16*)alloc(D * D * 2);
    u16*  WqkvhT = (u16*)alloc(3 * D * D * 2);     // combined (Wz@Wh)^T (3072x1024)
    u16*  WoT    = (u16*)alloc(D * D * 2);
    u16*  Wf1T   = (u16*)alloc(2 * D * D * 2);
    u16*  Wf2T   = (u16*)alloc(2 * D * D * 2);
    float* h     = (float*)alloc(S * D * 4);
    u16*  hbf    = (u16*)alloc(S * D * 2);
    u16*  qkvh   = (u16*)alloc(3 * S * D * 2);     // [Qh;Kh;V^T] (slab 2 = V^T e x s)
    u16*  ctx    = (u16*)alloc(S * D * 2);
    size_t baseEnd = off;

    size_t reg4 = (size_t)4 * S * S * 2;                       // 75.5 MB
    size_t reg1 = (size_t)S * S * 2 + (size_t)S * 2 * D * 2;   // 1-head scores + ffn1
    int HBv = (ws_size >= baseEnd + reg4 + 4096) ? 4 : 1;
    char* regionB = alloc(HBv == 4 ? reg4 : reg1);

    u16* scoresP = (u16*)regionB;
    u16* Wcat    = (u16*)regionB;                  // prep phase (scores dead)
    u16* woParts = (u16*)regionB;                  // 2 x (S*D) bf16 (scores dead)
    u16* ffn1;                                     // (S x 2048) bf16
    u16* f2Parts;                                  // 2 x (S*D) bf16
    if (HBv == 4){
        ffn1    = (u16*)regionB;
        f2Parts = (u16*)(regionB + (size_t)S * 2 * D * 2);
    } else {
        ffn1    = (u16*)(regionB + (size_t)S * S * 2);
        f2Parts = (u16*)regionB;                   // scores dead by FFN2
    }

    const long pSD = S * D;                        // elements per bf16 partial slab

    dim3 tb(32, 8);
    sniff_kernel<<<1, 256, 0, stream>>>((const u16*)hidden, flag);
    cvt_biases<<<(BIAS_TOT + 255) / 256, 256, 0, stream>>>(
        flag, bq, bk, bv, bh, bo, bf1, bf2, g1, b1n, g2, b2n, Whd, bhd, barena);
    init_h<<<(int)(S * D / 256), 256, 0, stream>>>(flag, hidden, h, hbf);

    for (int l = 0; l < L; ++l){
        // ---- prep: transposes + Wcat copy + rowSums zero (1 launch) ----
        wprep<<<7728, tb, 0, stream>>>(flag, l, Wo, Wf1, Wf2, Wh, Wq, Wk, Wv,
                                       WoT, Wf1T, Wf2T, WhT, Wcat, rowSums);
        gemm64<1, 0><<<dim3(16, 8, 3), 256, 0, stream>>>(
            WhT, 1024, Wcat, 1024, WqkvhT, 1024, nullptr,
            1024, 0, (long)D * D, (long)D * D, 0, nullptr);
        bias_combine<<<12, 256, 0, stream>>>(barena, WhT, l, bqkvh);

        // ---- fused QKV+head projection; V written transposed into slab 2 ----
        gemm64<1, 1><<<dim3(48, 24, 1), 256, 0, stream>>>(
            hbf, 1024, WqkvhT, 1024, qkvh, 0, bqkvh,
            1024, 0, 0, 0, 0, nullptr);

        // ---- attention: scores(+exp+rowsums), then ctx with fused /l ----
        if (HBv == 4){
            gemm_scores<<<dim3(24, 24, 4), 256, 0, stream>>>(
                qkvh, 1024, qkvh + S * D, 1024, scoresP, (int)S,
                rowSums, (int)DK, DK, DK, (long)S * S);
            gemm64<1, 3><<<dim3(48, 2, 4), 256, 0, stream>>>(
                scoresP, (int)S, qkvh + 2 * S * D, (int)S,
                ctx, 1024, nullptr, (int)S,
                (long)S * S, (long)DK * S, DK, 0, rowSums);
        } else {
            for (int h0 = 0; h0 < 4; ++h0){
                gemm_scores<<<dim3(24, 24, 1), 256, 0, stream>>>(
                    qkvh + h0 * DK, 1024, qkvh + S * D + h0 * DK, 1024,
                    scoresP, (int)S, rowSums + h0 * S, (int)DK, 0, 0, 0);
                gemm64<1, 3><<<dim3(48, 2, 1), 256, 0, stream>>>(
                    scoresP, (int)S, qkvh + 2 * S * D + (long)h0 * DK * S, (int)S,
                    ctx + h0 * DK, 1024, nullptr, (int)S,
                    0, 0, 0, 0, rowSums + h0 * S);
            }
        }

        // ---- attn_out: split-2 bf16 partials; reduce fused into LN ----
        gemm64<2, 0><<<dim3(48, 8, 2), 256, 0, stream>>>(
            ctx, 1024, WoT, 1024, woParts, 1024, nullptr,
            1024, 0, 0, 0, pSD, nullptr);
        ln_fused<<<3072, 256, 0, stream>>>(h, woParts, pSD, 2, barena + OFF_BO + l * D,
                                           hbf, barena + OFF_G1 + l * D, barena + OFF_B1N + l * D);
        // ---- FFN1: single gemm64, bias+ReLU fused ----
        gemm64<1, 2><<<dim3(48, 16, 1), 256, 0, stream>>>(
            hbf, 1024, Wf1T, 1024, ffn1, 2048, barena + OFF_BF1 + l * 2 * D,
            1024, 0, 0, 0, 0, nullptr);
        // ---- FFN2: split-2 bf16 partials; reduce fused into LN ----
        gemm64<2, 0><<<dim3(48, 8, 2), 256, 0, stream>>>(
            ffn1, 2048, Wf2T, 2048, f2Parts, 1024, nullptr,
            2048, 0, 0, 0, pSD, nullptr);
        ln_fused<<<3072, 256, 0, stream>>>(h, f2Parts, pSD, 2, barena + OFF_BF2 + l * D,
                                           hbf, barena + OFF_G2 + l * D, barena + OFF_B2N + l * D);
    }
    head_kernel<<<out_size, 256, 0, stream>>>(flag, h, barena, nePtr, naPtr, d_out);
}